// Round 11
// baseline (808.140 us; speedup 1.0000x reference)
//
#include <hip/hip_runtime.h>
#include <hip/hip_bf16.h>

#define BATCH 8192
#define IN_DIM 64
#define HID 1024
#define KTOT 1088   // HID + IN_DIM, fused K
#define NGATES 4096 // 4*HID, column c = 64*G + 16*g + q -> gate g of h=16*G+q
#define OMID 128
#define NP 256      // packed P rows (W1 0..127, W_halt 128, zeros)
#define MAX_ITER 8

#define TM 128
#define TN 128
#define TK 64
#define NBLK 512    // act_all grid: 2/CU guaranteed resident (launch_bounds),
                    // and R10's A/B proved 512 blocks reach gates plateau

typedef __attribute__((ext_vector_type(8))) short short8;
typedef __attribute__((ext_vector_type(4))) float float4v;

__device__ __forceinline__ float bf2f(short s) {
    union { float f; unsigned u; } v; v.u = ((unsigned)(unsigned short)s) << 16; return v.f;
}
__device__ __forceinline__ short f2bf(float f) {
    union { float f; unsigned u; } v; v.f = f;
    unsigned r = v.u + 0x7fff + ((v.u >> 16) & 1);  // round-to-nearest-even
    return (short)(r >> 16);
}
__device__ __forceinline__ float sigmoidf_(float x) {
    float xc = fminf(fmaxf(x, -30.f), 30.f);
    return 1.f / (1.f + __expf(-xc));
}
__device__ __forceinline__ float tanhf_(float x) {
    float xc = fminf(fmaxf(x, -15.f), 15.f);
    float e = __expf(2.f * xc);
    return (e - 1.f) / (e + 1.f);
}
__device__ __forceinline__ int aload(const int* p) {
    return __hip_atomic_load((int*)p, __ATOMIC_RELAXED, __HIP_MEMORY_SCOPE_AGENT);
}
__device__ __forceinline__ void astore(int* p, int v) {
    __hip_atomic_store(p, v, __ATOMIC_RELAXED, __HIP_MEMORY_SCOPE_AGENT);
}

// NBLK-block generation barrier. RELAXED polling by one lane per block with
// s_sleep (R7 lesson: per-iteration ACQUIRE invalidates from many spinners
// poison the memory system); release fence before the increment, single
// acquire load + fence after the spin. Validated at 64 blocks in R8
// (including a cnt/ridx data handoff across it); this round scales it to 512
// spinners -- polling traffic is one relaxed load/block/~256cyc, trivial.
__device__ __forceinline__ void gbar(int* bar, int phase, int tid) {
    __syncthreads();
    if (tid == 0) {
        __threadfence();   // release: publish this block's writes device-wide
        __hip_atomic_fetch_add(bar, 1, __ATOMIC_RELEASE, __HIP_MEMORY_SCOPE_AGENT);
        while (aload(bar) < NBLK * phase)
            __builtin_amdgcn_s_sleep(2);
        (void)__hip_atomic_load(bar, __ATOMIC_ACQUIRE, __HIP_MEMORY_SCOPE_AGENT);
        __threadfence();   // acquire: invalidate caches before reading others' data
    }
    __syncthreads();
}

// One gates GEMM tile (128 rows x 128 gate-cols) + fused LSTM cell update
// epilogue. LDS XOR swizzle (R2-verified: 0 bank conflicts). Trailing
// __syncthreads protects LDS for the caller's next tile.
__device__ __forceinline__ void gates_tile(
    short* As, short* Bs, int tid,
    const short* __restrict__ A, const short* __restrict__ B,
    const float* __restrict__ bias_g, int K,
    float* __restrict__ cell, short* __restrict__ Aout,
    const int* __restrict__ ridx, int n_act, int m0, int bx)
{
    const int wave = tid >> 6, lane = tid & 63;
    const int wm = wave & 1, wn = wave >> 1;
    const int colq = lane & 15, q = lane >> 4;
    const int lrow8 = lane >> 3;
    const int lk    = (((lane & 7) ^ lrow8) * 8);
    const int n0 = bx * TN;

    int aoff[4][2], boff[4][2];
#pragma unroll
    for (int i = 0; i < 4; ++i) {
        const int Ra = wm * 64 + i * 16 + colq;
        const int Rb = wn * 64 + i * 16 + colq;
#pragma unroll
        for (int c2 = 0; c2 < 2; ++c2) {
            const int C = q + 4 * c2;
            aoff[i][c2] = Ra * TK + ((C ^ (Ra & 7)) << 3);
            boff[i][c2] = Rb * TK + ((C ^ (Rb & 7)) << 3);
        }
    }

    float4v acc[4][4];
#pragma unroll
    for (int i = 0; i < 4; ++i)
#pragma unroll
        for (int j = 0; j < 4; ++j) acc[i][j] = (float4v)0.f;

    const short* ga[4];
    const short* gb[4];
#pragma unroll
    for (int it = 0; it < 4; ++it) {
        const int rr = (wave * 4 + it) * 8;
        ga[it] = A + (size_t)ridx[m0 + rr + lrow8] * KTOT + lk;
        gb[it] = B + (size_t)(n0 + rr + lrow8) * KTOT + lk;
    }

    for (int k0 = 0; k0 < K; k0 += TK) {
#pragma unroll
        for (int it = 0; it < 4; ++it) {
            const int rr = (wave * 4 + it) * 8;
            __builtin_amdgcn_global_load_lds(
                (const __attribute__((address_space(1))) void*)ga[it],
                (__attribute__((address_space(3))) void*)(As + rr * TK), 16, 0, 0);
            __builtin_amdgcn_global_load_lds(
                (const __attribute__((address_space(1))) void*)gb[it],
                (__attribute__((address_space(3))) void*)(Bs + rr * TK), 16, 0, 0);
            ga[it] += TK; gb[it] += TK;
        }
        __syncthreads();
#pragma unroll
        for (int c2 = 0; c2 < 2; ++c2) {
            short8 af[4], bf[4];
#pragma unroll
            for (int i = 0; i < 4; ++i) {
                af[i] = *(const short8*)(As + aoff[i][c2]);
                bf[i] = *(const short8*)(Bs + boff[i][c2]);
            }
#pragma unroll
            for (int i = 0; i < 4; ++i)
#pragma unroll
                for (int j = 0; j < 4; ++j)
                    acc[i][j] = __builtin_amdgcn_mfma_f32_16x16x32_bf16(af[i], bf[j], acc[i][j], 0, 0, 0);
        }
        __syncthreads();
    }

    const int G = bx * 2 + wn;   // 64-col group = 16 hidden units
    const int h = G * 16 + colq;
    const float bi  = bias_g[G * 64 +  0 + colq];
    const float bff = bias_g[G * 64 + 16 + colq];
    const float bc  = bias_g[G * 64 + 32 + colq];
    const float bo  = bias_g[G * 64 + 48 + colq];
#pragma unroll
    for (int i = 0; i < 4; ++i) {
        const int pbase = m0 + wm * 64 + i * 16 + q * 4;
#pragma unroll
        for (int r = 0; r < 4; ++r) {
            const int pos = pbase + r;
            if (pos < n_act) {
                const int row = ridx[pos];
                const float ig = sigmoidf_(acc[i][0][r] + bi);
                const float fg = sigmoidf_(acc[i][1][r] + bff);
                const float cg = tanhf_(acc[i][2][r] + bc);
                const float og = sigmoidf_(acc[i][3][r] + bo);
                const size_t ci = (size_t)row * HID + h;
                const float c = fg * cell[ci] + ig * cg;
                cell[ci] = c;
                Aout[(size_t)row * KTOT + h] = f2bf(og * tanhf_(c));
            }
        }
    }
    __syncthreads();   // protect As/Bs before caller's next tile
}

// One 128-row midfin tile: mid GEMM (128 cols = W1, K=HID) + W2-dot via
// shuffle+LDS reduction + halt-dot (state·W_halt fp32) + halting
// bookkeeping. red/hbuf alias As (only touched after the k-loop).
__device__ __forceinline__ void midfin_tile(
    short* As, short* Bs, int tid,
    const short* __restrict__ Anew, const short* __restrict__ P,
    const float* __restrict__ bias_p, const float* __restrict__ W_halt,
    const float* __restrict__ W2, const float* __restrict__ b2,
    float* __restrict__ outp, float* __restrict__ p_sum,
    const int* __restrict__ rprev, int* __restrict__ rnext,
    int* __restrict__ cnt, int t, int m0, int n_act)
{
    const int wave = tid >> 6, lane = tid & 63;
    const int wm = wave & 1, wn = wave >> 1;
    const int colq = lane & 15, q = lane >> 4;
    const int lrow8 = lane >> 3;
    const int lk    = (((lane & 7) ^ lrow8) * 8);

    float4v acc[4][4];
#pragma unroll
    for (int i = 0; i < 4; ++i)
#pragma unroll
        for (int j = 0; j < 4; ++j) acc[i][j] = (float4v)0.f;

    const short* ga[4];
    const short* gb[4];
#pragma unroll
    for (int it = 0; it < 4; ++it) {
        const int rr = (wave * 4 + it) * 8;
        ga[it] = Anew + (size_t)rprev[m0 + rr + lrow8] * KTOT + lk;
        gb[it] = P + (size_t)(rr + lrow8) * HID + lk;
    }
    int aoff[4][2], boff[4][2];
#pragma unroll
    for (int i = 0; i < 4; ++i) {
        const int Ra = wm * 64 + i * 16 + colq;
        const int Rb = wn * 64 + i * 16 + colq;
#pragma unroll
        for (int c2 = 0; c2 < 2; ++c2) {
            const int C = q + 4 * c2;
            aoff[i][c2] = Ra * TK + ((C ^ (Ra & 7)) << 3);
            boff[i][c2] = Rb * TK + ((C ^ (Rb & 7)) << 3);
        }
    }

    for (int k0 = 0; k0 < HID; k0 += TK) {
#pragma unroll
        for (int it = 0; it < 4; ++it) {
            const int rr = (wave * 4 + it) * 8;
            __builtin_amdgcn_global_load_lds(
                (const __attribute__((address_space(1))) void*)ga[it],
                (__attribute__((address_space(3))) void*)(As + rr * TK), 16, 0, 0);
            __builtin_amdgcn_global_load_lds(
                (const __attribute__((address_space(1))) void*)gb[it],
                (__attribute__((address_space(3))) void*)(Bs + rr * TK), 16, 0, 0);
            ga[it] += TK; gb[it] += TK;
        }
        __syncthreads();
#pragma unroll
        for (int c2 = 0; c2 < 2; ++c2) {
            short8 af[4], bf[4];
#pragma unroll
            for (int i = 0; i < 4; ++i) {
                af[i] = *(const short8*)(As + aoff[i][c2]);
                bf[i] = *(const short8*)(Bs + boff[i][c2]);
            }
#pragma unroll
            for (int i = 0; i < 4; ++i)
#pragma unroll
                for (int j = 0; j < 4; ++j)
                    acc[i][j] = __builtin_amdgcn_mfma_f32_16x16x32_bf16(af[i], bf[j], acc[i][j], 0, 0, 0);
        }
        __syncthreads();
    }

    // aliases over As (k-loop done; last barrier above protects)
    float* red  = (float*)As;           // 256 floats: [wn][wm][i][q][r]
    float* hbuf = ((float*)As) + 256;   // 128 floats

    // halt-dot: per row, state · W_halt
    for (int s = 0; s < 32; ++s) {
        const int lr = wave * 32 + s;
        const int row = rprev[m0 + lr];
        const short* Ar = Anew + (size_t)row * KTOT + lane * 16;
        const short8 v0 = *(const short8*)Ar;
        const short8 v1 = *(const short8*)(Ar + 8);
        const float* Wh = W_halt + lane * 16;
        float hv = 0.f;
#pragma unroll
        for (int e = 0; e < 8; ++e) hv += bf2f(v0[e]) * Wh[e];
#pragma unroll
        for (int e = 0; e < 8; ++e) hv += bf2f(v1[e]) * Wh[8 + e];
#pragma unroll
        for (int o = 32; o > 0; o >>= 1) hv += __shfl_down(hv, o);
        if (lane == 0) hbuf[lr] = hv;
    }

    // relu + W2-dot, reduce over cols
    float pr[4][4];
#pragma unroll
    for (int i = 0; i < 4; ++i)
#pragma unroll
        for (int r = 0; r < 4; ++r) pr[i][r] = 0.f;
#pragma unroll
    for (int j = 0; j < 4; ++j) {
        const int col = wn * 64 + j * 16 + colq;
        const float b = bias_p[col];
        const float w2 = W2[col];
#pragma unroll
        for (int i = 0; i < 4; ++i)
#pragma unroll
            for (int r = 0; r < 4; ++r)
                pr[i][r] += fmaxf(acc[i][j][r] + b, 0.f) * w2;
    }
#pragma unroll
    for (int i = 0; i < 4; ++i)
#pragma unroll
        for (int r = 0; r < 4; ++r) {
            float v = pr[i][r];
            v += __shfl_down(v, 8, 16);
            v += __shfl_down(v, 4, 16);
            v += __shfl_down(v, 2, 16);
            v += __shfl_down(v, 1, 16);
            if (colq == 0)
                red[((((wn * 2) + wm) * 4 + i) * 4 + q) * 4 + r] = v;
        }
    __syncthreads();

    // finalize: one thread per row
    if (tid < TM) {
        const int pos = m0 + tid;
        if (pos < n_act) {
            const int lwm = tid >> 6, i = (tid >> 4) & 3, lq = (tid >> 2) & 3, r = tid & 3;
            const float odot = red[((lwm * 4 + i) * 4 + lq) * 4 + r]
                             + red[(((2 + lwm) * 4 + i) * 4 + lq) * 4 + r];
            const int row = rprev[pos];
            const float ov = sigmoidf_(odot + b2[0]);
            const float h  = sigmoidf_(hbuf[tid] + bias_p[OMID]);
            const float ps = p_sum[row];
            const float pn = ps + h;
            const bool fin = (pn >= 1.f - 1e-3f) || (t == MAX_ITER - 1);
            const float halt = fin ? (1.f - ps) : h;
            outp[row] += ov * halt;
            p_sum[row] = fin ? 1.f : pn;
            if (!fin) {
                const int d = atomicAdd(&cnt[t + 1], 1);
                astore(&rnext[d], row);
            }
        }
    }
    __syncthreads();   // protect As/Bs aliases before caller reuses LDS
}

// Persistent 512-block kernel: the ENTIRE 8-step ACT loop. Per live step:
// gates phase (all blocks, tile-strided) -> gbar -> midfin phase -> gbar.
// Steps with cnt[t]==0 break uniformly (all blocks see the same count after
// the barrier). t=0 uses the x-part shortcut (state==0 -> K=64).
// 512 blocks: co-residency guaranteed by __launch_bounds__(256,2) (>=2
// blocks/CU x 256 CUs), and R10's GY A/B proved 512 blocks reach the gates
// throughput plateau. This trades 7 dispatch boundaries (launch + full L2
// drain/ramp each) for 6 in-kernel barriers whose data flush is work we pay
// either way.
__global__ __launch_bounds__(256, 2) void act_all(
    const short* __restrict__ Wg, const float* __restrict__ bias_g,
    const short* __restrict__ P, const float* __restrict__ bias_p,
    const float* __restrict__ W_halt, const float* __restrict__ W2,
    const float* __restrict__ b2,
    short* __restrict__ A0, short* __restrict__ A1,
    float* __restrict__ cell, float* __restrict__ outp,
    float* __restrict__ p_sum,
    int* __restrict__ ridx0, int* __restrict__ ridx1,
    int* __restrict__ cnt, int* __restrict__ bar)
{
    __shared__ short As[TM * TK];
    __shared__ short Bs[TN * TK];
    const int tid = threadIdx.x;
    int phase = 0;

    for (int t = 0; t < MAX_ITER; ++t) {
        const int n = aload(&cnt[t]);   // uniform (post-barrier / post-setup)
        if (n == 0) break;
        const short* Ain = (t & 1) ? A1 : A0;
        short*       Aot = (t & 1) ? A0 : A1;
        const int* Lt = (t & 1) ? ridx1 : ridx0;   // active list for step t
        int*       Ln = (t & 1) ? ridx0 : ridx1;   // list for step t+1

        // ---- gates phase (t=0: state==0 -> x-part only, K=64) ----
        const short* Ause = (t == 0) ? Ain + HID : Ain;
        const short* Buse = (t == 0) ? Wg + HID : Wg;
        const int Kuse = (t == 0) ? IN_DIM : KTOT;
        const int ntiles = ((n + TM - 1) / TM) * (NGATES / TN);
        for (int e = blockIdx.x; e < ntiles; e += gridDim.x)
            gates_tile(As, Bs, tid, Ause, Buse, bias_g, Kuse, cell, Aot,
                       Lt, n, (e >> 5) * TM, e & 31);
        ++phase; gbar(bar, phase, tid);   // publish Aot/cell

        // ---- midfin phase ----
        for (int tile = blockIdx.x; tile * TM < n; tile += gridDim.x)
            midfin_tile(As, Bs, tid, Aot, P, bias_p, W_halt, W2, b2,
                        outp, p_sum, Lt, Ln, cnt, t, tile * TM, n);
        if (t == MAX_ITER - 1) break;
        ++phase; gbar(bar, phase, tid);   // publish cnt[t+1]/ridx/p_sum/outp
    }
}

// one dispatch for all setup: weight packing + A/cell/bookkeeping init
#define SETUP_INIT  (BATCH * KTOT)
#define SETUP_WG    (NGATES * KTOT)
#define SETUP_P     (NP * HID)
#define SETUP_TOT   (SETUP_INIT + SETUP_WG + SETUP_P)
__global__ __launch_bounds__(256) void setup_k(
    const float* __restrict__ x,
    const float* __restrict__ Whi, const float* __restrict__ Whf,
    const float* __restrict__ Whc, const float* __restrict__ Who,
    const float* __restrict__ Wxi, const float* __restrict__ Wxf,
    const float* __restrict__ Wxc, const float* __restrict__ Wxo,
    const float* __restrict__ bxi, const float* __restrict__ bhi,
    const float* __restrict__ bxf, const float* __restrict__ bhf,
    const float* __restrict__ bxc, const float* __restrict__ bhc,
    const float* __restrict__ bxo, const float* __restrict__ bho,
    const float* __restrict__ W1, const float* __restrict__ b1,
    const float* __restrict__ W_halt, const float* __restrict__ b_halt,
    short* __restrict__ A0, short* __restrict__ A1,
    float* __restrict__ cell, float* __restrict__ p_sum,
    int* __restrict__ ridx0, int* __restrict__ ridx1, int* __restrict__ cnt,
    int* __restrict__ bar, float* __restrict__ outp,
    short* __restrict__ Wg, float* __restrict__ bias_g,
    short* __restrict__ P, float* __restrict__ bias_p)
{
    int idx = blockIdx.x * 256 + threadIdx.x;
    if (idx < SETUP_INIT) {
        const int row = idx / KTOT, k = idx - row * KTOT;
        const short v = (k < HID) ? (short)0 : f2bf(x[row * IN_DIM + (k - HID)]);
        A0[idx] = v;
        A1[idx] = v;   // x cols iteration-invariant; state part overwritten each step
        if (k < HID) cell[(size_t)row * HID + k] = 0.f;
        if (k == 0) {
            p_sum[row] = 0.f;
            outp[row] = 0.f;
            ridx0[row] = row;   // step 0: identity compaction
            ridx1[row] = 0;     // in-range dummies for padded tile reads
        }
        if (row == 0 && k <= MAX_ITER) cnt[k] = (k == 0) ? BATCH : 0;
        if (row == 1 && k == 0) bar[0] = 0;
        return;
    }
    idx -= SETUP_INIT;
    if (idx < SETUP_WG) {
        const int n = idx / KTOT, k = idx - n * KTOT;
        // interleaved layout: n = 64*G + 16*g + q  ->  gate g of hidden h=16*G+q
        const int G = n >> 6, g = (n >> 4) & 3, q = n & 15;
        const int h = G * 16 + q;
        const float* Wh = (g == 0) ? Whi : (g == 1) ? Whf : (g == 2) ? Whc : Who;
        const float* Wx = (g == 0) ? Wxi : (g == 1) ? Wxf : (g == 2) ? Wxc : Wxo;
        const float v = (k < HID) ? Wh[h * HID + k] : Wx[h * IN_DIM + (k - HID)];
        Wg[idx] = f2bf(v);
        if (k == 0) {
            const float* bx = (g == 0) ? bxi : (g == 1) ? bxf : (g == 2) ? bxc : bxo;
            const float* bh = (g == 0) ? bhi : (g == 1) ? bhf : (g == 2) ? bhc : bho;
            bias_g[n] = bx[h] + bh[h];
        }
        return;
    }
    idx -= SETUP_WG;
    if (idx < SETUP_P) {
        const int n = idx >> 10, k = idx & 1023;
        const float v = (n < OMID) ? W1[n * HID + k] : (n == OMID ? W_halt[k] : 0.f);
        P[idx] = f2bf(v);
        if (k == 0) bias_p[n] = (n < OMID) ? b1[n] : (n == OMID ? b_halt[0] : 0.f);
    }
}

extern "C" void kernel_launch(void* const* d_in, const int* in_sizes, int n_in,
                              void* d_out, int out_size, void* d_ws, size_t ws_size,
                              hipStream_t stream) {
    const float* x    = (const float*)d_in[0];
    const float* Wxi  = (const float*)d_in[1];
    const float* bxi  = (const float*)d_in[2];
    const float* Whi  = (const float*)d_in[3];
    const float* bhi  = (const float*)d_in[4];
    const float* Wxf  = (const float*)d_in[5];
    const float* bxf  = (const float*)d_in[6];
    const float* Whf  = (const float*)d_in[7];
    const float* bhf  = (const float*)d_in[8];
    const float* Wxc  = (const float*)d_in[9];
    const float* bxc  = (const float*)d_in[10];
    const float* Whc  = (const float*)d_in[11];
    const float* bhc  = (const float*)d_in[12];
    const float* Wxo  = (const float*)d_in[13];
    const float* bxo  = (const float*)d_in[14];
    const float* Who  = (const float*)d_in[15];
    const float* bho  = (const float*)d_in[16];
    const float* W_halt = (const float*)d_in[17];
    const float* b_halt = (const float*)d_in[18];
    const float* W1   = (const float*)d_in[19];
    const float* b1   = (const float*)d_in[20];
    const float* W2   = (const float*)d_in[21];
    const float* b2   = (const float*)d_in[22];

    char* p = (char*)d_ws;
    auto carve = [&](size_t bytes) { char* r = p; p += (bytes + 255) & ~(size_t)255; return r; };
    short* A0     = (short*)carve((size_t)BATCH * KTOT * 2);
    short* A1     = (short*)carve((size_t)BATCH * KTOT * 2);
    short* Wg     = (short*)carve((size_t)NGATES * KTOT * 2);
    float* bias_g = (float*)carve((size_t)NGATES * 4);
    short* P      = (short*)carve((size_t)NP * HID * 2);
    float* bias_p = (float*)carve((size_t)NP * 4);
    float* cell   = (float*)carve((size_t)BATCH * HID * 4);
    float* p_sum  = (float*)carve((size_t)BATCH * 4);
    int*   ridx0  = (int*)carve((size_t)BATCH * 4);
    int*   ridx1  = (int*)carve((size_t)BATCH * 4);
    int*   cnt    = (int*)carve((size_t)(MAX_ITER + 1) * 4);
    int*   bar    = (int*)carve(256);
    float* outp   = (float*)d_out;

    setup_k<<<(SETUP_TOT + 255) / 256, 256, 0, stream>>>(
        x, Whi, Whf, Whc, Who, Wxi, Wxf, Wxc, Wxo,
        bxi, bhi, bxf, bhf, bxc, bhc, bxo, bho,
        W1, b1, W_halt, b_halt,
        A0, A1, cell, p_sum, ridx0, ridx1, cnt, bar, outp,
        Wg, bias_g, P, bias_p);

    act_all<<<NBLK, 256, 0, stream>>>(
        Wg, bias_g, P, bias_p, W_halt, W2, b2,
        A0, A1, cell, outp, p_sum, ridx0, ridx1, cnt, bar);
}

// Round 12
// 730.188 us; speedup vs baseline: 1.1068x; 1.1068x over previous
//
#include <hip/hip_runtime.h>
#include <hip/hip_bf16.h>

#define BATCH 8192
#define IN_DIM 64
#define HID 1024
#define KTOT 1088   // HID + IN_DIM, fused K
#define NGATES 4096 // 4*HID, column c = 64*G + 16*g + q -> gate g of h=16*G+q
#define OMID 128
#define NP 256      // packed P rows (W1 0..127, W_halt 128, zeros)
#define MAX_ITER 8

#define TM 128
#define TN 128
#define TK 64
#define TAILB 64    // tail_k blocks: few enough that a device barrier is cheap

typedef __attribute__((ext_vector_type(8))) short short8;
typedef __attribute__((ext_vector_type(4))) float float4v;

__device__ __forceinline__ float bf2f(short s) {
    union { float f; unsigned u; } v; v.u = ((unsigned)(unsigned short)s) << 16; return v.f;
}
__device__ __forceinline__ short f2bf(float f) {
    union { float f; unsigned u; } v; v.f = f;
    unsigned r = v.u + 0x7fff + ((v.u >> 16) & 1);  // round-to-nearest-even
    return (short)(r >> 16);
}
__device__ __forceinline__ float sigmoidf_(float x) {
    float xc = fminf(fmaxf(x, -30.f), 30.f);
    return 1.f / (1.f + __expf(-xc));
}
__device__ __forceinline__ float tanhf_(float x) {
    float xc = fminf(fmaxf(x, -15.f), 15.f);
    float e = __expf(2.f * xc);
    return (e - 1.f) / (e + 1.f);
}
__device__ __forceinline__ int aload(const int* p) {
    return __hip_atomic_load((int*)p, __ATOMIC_RELAXED, __HIP_MEMORY_SCOPE_AGENT);
}
__device__ __forceinline__ void astore(int* p, int v) {
    __hip_atomic_store(p, v, __ATOMIC_RELAXED, __HIP_MEMORY_SCOPE_AGENT);
}

// 64-block generation barrier (R8-verified; R5/R7/R11 proved ANY wider
// barrier pays 50-100us in cross-XCD L2 invalidate traffic). RELAXED polling
// by one lane per block with s_sleep; fences only at the crossing points.
__device__ __forceinline__ void gbar(int* bar, int phase, int tid) {
    __syncthreads();
    if (tid == 0) {
        __threadfence();
        __hip_atomic_fetch_add(bar, 1, __ATOMIC_ACQ_REL, __HIP_MEMORY_SCOPE_AGENT);
        while (aload(bar) < TAILB * phase)
            __builtin_amdgcn_s_sleep(8);
        __threadfence();
    }
    __syncthreads();
}

// One gates GEMM tile (128 rows x 128 gate-cols) + fused LSTM cell update.
// LDS-FREE: each lane loads its MFMA fragments directly global->VGPR
// (A-operand layout: lane holds row m=lane&15, k = (lane>>4)*8..+8 — a
// 16B short8). No __syncthreads in the k-loop at all. Rationale (R10 A/B +
// cycle accounting): the staged path was limited by per-CU LDS bandwidth +
// 34 vmcnt(0)-drain barriers per tile, ~98% overhead at K=17 iters; B/A
// cross-block reuse is served by L2 (34.5 TB/s, ~2x headroom) instead of
// LDS. Accumulation order identical to the staged version (bit-exact).
__device__ __forceinline__ void gates_tile(
    int tid,
    const short* __restrict__ A,
    const short* __restrict__ B,
    const float* __restrict__ bias_g, int K,
    float* __restrict__ cell, short* __restrict__ Aout,
    const int* __restrict__ ridx, int n_act, int m0, int bx)
{
    const int wave = tid >> 6, lane = tid & 63;
    const int wm = wave & 1, wn = wave >> 1;
    const int colq = lane & 15, q = lane >> 4;

    // fragment row pointers (A rows indirected through the compacted list;
    // entries beyond n_act are valid in-range dummies -> harmless reads)
    const short* pa[4];
    const short* pb[4];
#pragma unroll
    for (int i = 0; i < 4; ++i) {
        pa[i] = A + (size_t)ridx[m0 + wm * 64 + i * 16 + colq] * KTOT + q * 8;
        pb[i] = B + (size_t)(bx * TN + wn * 64 + i * 16 + colq) * KTOT + q * 8;
    }

    float4v acc[4][4];
#pragma unroll
    for (int i = 0; i < 4; ++i)
#pragma unroll
        for (int j = 0; j < 4; ++j) acc[i][j] = (float4v)0.f;

    for (int k0 = 0; k0 < K; k0 += 32) {
        short8 af[4], bf[4];
#pragma unroll
        for (int i = 0; i < 4; ++i) af[i] = *(const short8*)(pa[i] + k0);
#pragma unroll
        for (int j = 0; j < 4; ++j) bf[j] = *(const short8*)(pb[j] + k0);
#pragma unroll
        for (int i = 0; i < 4; ++i)
#pragma unroll
            for (int j = 0; j < 4; ++j)
                acc[i][j] = __builtin_amdgcn_mfma_f32_16x16x32_bf16(af[i], bf[j], acc[i][j], 0, 0, 0);
    }

    const int G = bx * 2 + wn;   // 64-col group = 16 hidden units
    const int h = G * 16 + colq;
    const float bi  = bias_g[G * 64 +  0 + colq];
    const float bff = bias_g[G * 64 + 16 + colq];
    const float bc  = bias_g[G * 64 + 32 + colq];
    const float bo  = bias_g[G * 64 + 48 + colq];
#pragma unroll
    for (int i = 0; i < 4; ++i) {
        const int pbase = m0 + wm * 64 + i * 16 + q * 4;
#pragma unroll
        for (int r = 0; r < 4; ++r) {
            const int pos = pbase + r;
            if (pos < n_act) {
                const int row = ridx[pos];
                const float ig = sigmoidf_(acc[i][0][r] + bi);
                const float fg = sigmoidf_(acc[i][1][r] + bff);
                const float cg = tanhf_(acc[i][2][r] + bc);
                const float og = sigmoidf_(acc[i][3][r] + bo);
                const size_t ci = (size_t)row * HID + h;
                const float c = fg * cell[ci] + ig * cg;
                cell[ci] = c;
                Aout[(size_t)row * KTOT + h] = f2bf(og * tanhf_(c));
            }
        }
    }
}

// One 128-row midfin tile: mid GEMM (128 cols = W1, K=HID) + W2-dot via
// shuffle+LDS reduction + halt-dot (state·W_halt fp32) + halting
// bookkeeping. Staged-LDS path kept (proven; not on the critical path).
// red/hbuf alias As (only touched after the k-loop).
__device__ __forceinline__ void midfin_tile(
    short* As, short* Bs, int tid,
    const short* __restrict__ Anew, const short* __restrict__ P,
    const float* __restrict__ bias_p, const float* __restrict__ W_halt,
    const float* __restrict__ W2, const float* __restrict__ b2,
    float* __restrict__ outp, float* __restrict__ p_sum,
    const int* __restrict__ rprev, int* __restrict__ rnext,
    int* __restrict__ cnt, int t, int m0, int n_act)
{
    const int wave = tid >> 6, lane = tid & 63;
    const int wm = wave & 1, wn = wave >> 1;
    const int colq = lane & 15, q = lane >> 4;
    const int lrow8 = lane >> 3;
    const int lk    = (((lane & 7) ^ lrow8) * 8);

    float4v acc[4][4];
#pragma unroll
    for (int i = 0; i < 4; ++i)
#pragma unroll
        for (int j = 0; j < 4; ++j) acc[i][j] = (float4v)0.f;

    const short* ga[4];
    const short* gb[4];
#pragma unroll
    for (int it = 0; it < 4; ++it) {
        const int rr = (wave * 4 + it) * 8;
        ga[it] = Anew + (size_t)rprev[m0 + rr + lrow8] * KTOT + lk;
        gb[it] = P + (size_t)(rr + lrow8) * HID + lk;
    }
    int aoff[4][2], boff[4][2];
#pragma unroll
    for (int i = 0; i < 4; ++i) {
        const int Ra = wm * 64 + i * 16 + colq;
        const int Rb = wn * 64 + i * 16 + colq;
#pragma unroll
        for (int c2 = 0; c2 < 2; ++c2) {
            const int C = q + 4 * c2;
            aoff[i][c2] = Ra * TK + ((C ^ (Ra & 7)) << 3);
            boff[i][c2] = Rb * TK + ((C ^ (Rb & 7)) << 3);
        }
    }

    for (int k0 = 0; k0 < HID; k0 += TK) {
#pragma unroll
        for (int it = 0; it < 4; ++it) {
            const int rr = (wave * 4 + it) * 8;
            __builtin_amdgcn_global_load_lds(
                (const __attribute__((address_space(1))) void*)ga[it],
                (__attribute__((address_space(3))) void*)(As + rr * TK), 16, 0, 0);
            __builtin_amdgcn_global_load_lds(
                (const __attribute__((address_space(1))) void*)gb[it],
                (__attribute__((address_space(3))) void*)(Bs + rr * TK), 16, 0, 0);
            ga[it] += TK; gb[it] += TK;
        }
        __syncthreads();
#pragma unroll
        for (int c2 = 0; c2 < 2; ++c2) {
            short8 af[4], bf[4];
#pragma unroll
            for (int i = 0; i < 4; ++i) {
                af[i] = *(const short8*)(As + aoff[i][c2]);
                bf[i] = *(const short8*)(Bs + boff[i][c2]);
            }
#pragma unroll
            for (int i = 0; i < 4; ++i)
#pragma unroll
                for (int j = 0; j < 4; ++j)
                    acc[i][j] = __builtin_amdgcn_mfma_f32_16x16x32_bf16(af[i], bf[j], acc[i][j], 0, 0, 0);
        }
        __syncthreads();
    }

    // aliases over As (k-loop done; last barrier above protects)
    float* red  = (float*)As;           // 256 floats: [wn][wm][i][q][r]
    float* hbuf = ((float*)As) + 256;   // 128 floats

    // halt-dot: per row, state · W_halt
    for (int s = 0; s < 32; ++s) {
        const int lr = wave * 32 + s;
        const int row = rprev[m0 + lr];
        const short* Ar = Anew + (size_t)row * KTOT + lane * 16;
        const short8 v0 = *(const short8*)Ar;
        const short8 v1 = *(const short8*)(Ar + 8);
        const float* Wh = W_halt + lane * 16;
        float hv = 0.f;
#pragma unroll
        for (int e = 0; e < 8; ++e) hv += bf2f(v0[e]) * Wh[e];
#pragma unroll
        for (int e = 0; e < 8; ++e) hv += bf2f(v1[e]) * Wh[8 + e];
#pragma unroll
        for (int o = 32; o > 0; o >>= 1) hv += __shfl_down(hv, o);
        if (lane == 0) hbuf[lr] = hv;
    }

    // relu + W2-dot, reduce over cols
    float pr[4][4];
#pragma unroll
    for (int i = 0; i < 4; ++i)
#pragma unroll
        for (int r = 0; r < 4; ++r) pr[i][r] = 0.f;
#pragma unroll
    for (int j = 0; j < 4; ++j) {
        const int col = wn * 64 + j * 16 + colq;
        const float b = bias_p[col];
        const float w2 = W2[col];
#pragma unroll
        for (int i = 0; i < 4; ++i)
#pragma unroll
            for (int r = 0; r < 4; ++r)
                pr[i][r] += fmaxf(acc[i][j][r] + b, 0.f) * w2;
    }
#pragma unroll
    for (int i = 0; i < 4; ++i)
#pragma unroll
        for (int r = 0; r < 4; ++r) {
            float v = pr[i][r];
            v += __shfl_down(v, 8, 16);
            v += __shfl_down(v, 4, 16);
            v += __shfl_down(v, 2, 16);
            v += __shfl_down(v, 1, 16);
            if (colq == 0)
                red[((((wn * 2) + wm) * 4 + i) * 4 + q) * 4 + r] = v;
        }
    __syncthreads();

    // finalize: one thread per row
    if (tid < TM) {
        const int pos = m0 + tid;
        if (pos < n_act) {
            const int lwm = tid >> 6, i = (tid >> 4) & 3, lq = (tid >> 2) & 3, r = tid & 3;
            const float odot = red[((lwm * 4 + i) * 4 + lq) * 4 + r]
                             + red[(((2 + lwm) * 4 + i) * 4 + lq) * 4 + r];
            const int row = rprev[pos];
            const float ov = sigmoidf_(odot + b2[0]);
            const float h  = sigmoidf_(hbuf[tid] + bias_p[OMID]);
            const float ps = p_sum[row];
            const float pn = ps + h;
            const bool fin = (pn >= 1.f - 1e-3f) || (t == MAX_ITER - 1);
            const float halt = fin ? (1.f - ps) : h;
            outp[row] += ov * halt;
            p_sum[row] = fin ? 1.f : pn;
            if (!fin) {
                const int d = atomicAdd(&cnt[t + 1], 1);
                astore(&rnext[d], row);
            }
        }
    }
    __syncthreads();   // protect As/Bs aliases before caller reuses LDS
}

// Standalone gates GEMM dispatch (steps 0..2). LDS-free. t=0
// host-special-cased: A,B offset by HID, K=64 (state==0).
__global__ __launch_bounds__(256) void gates_k(
    const short* __restrict__ A, const short* __restrict__ B,
    const float* __restrict__ bias_g, int K,
    float* __restrict__ cell, short* __restrict__ Aout,
    const int* __restrict__ ridx, const int* __restrict__ cnt, int t)
{
    const int n_act = cnt[t];
    for (int by = blockIdx.y; by * TM < n_act; by += gridDim.y)
        gates_tile(threadIdx.x, A, B, bias_g, K, cell, Aout,
                   ridx, n_act, by * TM, blockIdx.x);
}

// Standalone midfin dispatch (steps 0..1).
__global__ __launch_bounds__(256) void midfin_k(
    const short* __restrict__ Anew, const short* __restrict__ P,
    const float* __restrict__ bias_p, const float* __restrict__ W_halt,
    const float* __restrict__ W2, const float* __restrict__ b2,
    float* __restrict__ outp, float* __restrict__ p_sum,
    const int* __restrict__ rprev, int* __restrict__ rnext,
    int* __restrict__ cnt, int t)
{
    __shared__ short As[TM * TK];
    __shared__ short Bs[TN * TK];
    const int n_act = cnt[t];
    for (int tile = blockIdx.x; tile * TM < n_act; tile += gridDim.x)
        midfin_tile(As, Bs, threadIdx.x, Anew, P, bias_p, W_halt, W2, b2,
                    outp, p_sum, rprev, rnext, cnt, t, tile * TM, n_act);
}

// Persistent 64-block tail: midfin(2) + steps 3..7 (gates+midfin) with
// in-kernel barriers. For this data cnt[3]==0 so the generic loop exits
// after midfin(2)+1 barrier; full loop retained for arbitrary data.
__global__ __launch_bounds__(256) void tail_k(
    const short* __restrict__ Wg, const float* __restrict__ bias_g,
    const short* __restrict__ P, const float* __restrict__ bias_p,
    const float* __restrict__ W_halt, const float* __restrict__ W2,
    const float* __restrict__ b2,
    short* __restrict__ A0, short* __restrict__ A1,
    float* __restrict__ cell, float* __restrict__ outp,
    float* __restrict__ p_sum,
    int* __restrict__ ridx0, int* __restrict__ ridx1,
    int* __restrict__ cnt, int* __restrict__ bar)
{
    __shared__ short As[TM * TK];
    __shared__ short Bs[TN * TK];
    const int tid = threadIdx.x;
    int phase = 0;
    int t = 2;
    while (true) {
        short* Anew = (t & 1) ? A0 : A1;        // state written by gates(t)
        const int* rprev = (t & 1) ? ridx1 : ridx0;  // L_t
        int* rnext = (t & 1) ? ridx0 : ridx1;        // L_{t+1}
        const int n = aload(&cnt[t]);
        for (int tile = blockIdx.x; tile * TM < n; tile += gridDim.x)
            midfin_tile(As, Bs, tid, Anew, P, bias_p, W_halt, W2, b2,
                        outp, p_sum, rprev, rnext, cnt, t, tile * TM, n);
        if (t == MAX_ITER - 1) break;
        ++phase; gbar(bar, phase, tid);          // publish cnt[t+1], ridx, p_sum
        const int n1 = aload(&cnt[t + 1]);
        if (n1 == 0) break;                      // uniform across blocks
        {
            short* Aot = (t & 1) ? A1 : A0;
            const int ntiles = ((n1 + TM - 1) / TM) * (NGATES / TN);
            for (int e = blockIdx.x; e < ntiles; e += gridDim.x)
                gates_tile(tid, Anew, Wg, bias_g, KTOT, cell, Aot,
                           rnext, n1, (e >> 5) * TM, e & 31);
        }
        ++phase; gbar(bar, phase, tid);          // publish Aout, cell
        ++t;
    }
}

// one dispatch for all setup: weight packing + A/cell/bookkeeping init
#define SETUP_INIT  (BATCH * KTOT)
#define SETUP_WG    (NGATES * KTOT)
#define SETUP_P     (NP * HID)
#define SETUP_TOT   (SETUP_INIT + SETUP_WG + SETUP_P)
__global__ __launch_bounds__(256) void setup_k(
    const float* __restrict__ x,
    const float* __restrict__ Whi, const float* __restrict__ Whf,
    const float* __restrict__ Whc, const float* __restrict__ Who,
    const float* __restrict__ Wxi, const float* __restrict__ Wxf,
    const float* __restrict__ Wxc, const float* __restrict__ Wxo,
    const float* __restrict__ bxi, const float* __restrict__ bhi,
    const float* __restrict__ bxf, const float* __restrict__ bhf,
    const float* __restrict__ bxc, const float* __restrict__ bhc,
    const float* __restrict__ bxo, const float* __restrict__ bho,
    const float* __restrict__ W1, const float* __restrict__ b1,
    const float* __restrict__ W_halt, const float* __restrict__ b_halt,
    short* __restrict__ A0, short* __restrict__ A1,
    float* __restrict__ cell, float* __restrict__ p_sum,
    int* __restrict__ ridx0, int* __restrict__ ridx1, int* __restrict__ cnt,
    int* __restrict__ bar, float* __restrict__ outp,
    short* __restrict__ Wg, float* __restrict__ bias_g,
    short* __restrict__ P, float* __restrict__ bias_p)
{
    int idx = blockIdx.x * 256 + threadIdx.x;
    if (idx < SETUP_INIT) {
        const int row = idx / KTOT, k = idx - row * KTOT;
        const short v = (k < HID) ? (short)0 : f2bf(x[row * IN_DIM + (k - HID)]);
        A0[idx] = v;
        A1[idx] = v;   // x cols iteration-invariant; state part overwritten each step
        if (k < HID) cell[(size_t)row * HID + k] = 0.f;
        if (k == 0) {
            p_sum[row] = 0.f;
            outp[row] = 0.f;
            ridx0[row] = row;   // step 0: identity compaction
            ridx1[row] = 0;     // in-range dummies for padded tile reads
        }
        if (row == 0 && k <= MAX_ITER) cnt[k] = (k == 0) ? BATCH : 0;
        if (row == 1 && k == 0) bar[0] = 0;
        return;
    }
    idx -= SETUP_INIT;
    if (idx < SETUP_WG) {
        const int n = idx / KTOT, k = idx - n * KTOT;
        // interleaved layout: n = 64*G + 16*g + q  ->  gate g of hidden h=16*G+q
        const int G = n >> 6, g = (n >> 4) & 3, q = n & 15;
        const int h = G * 16 + q;
        const float* Wh = (g == 0) ? Whi : (g == 1) ? Whf : (g == 2) ? Whc : Who;
        const float* Wx = (g == 0) ? Wxi : (g == 1) ? Wxf : (g == 2) ? Wxc : Wxo;
        const float v = (k < HID) ? Wh[h * HID + k] : Wx[h * IN_DIM + (k - HID)];
        Wg[idx] = f2bf(v);
        if (k == 0) {
            const float* bx = (g == 0) ? bxi : (g == 1) ? bxf : (g == 2) ? bxc : bxo;
            const float* bh = (g == 0) ? bhi : (g == 1) ? bhf : (g == 2) ? bhc : bho;
            bias_g[n] = bx[h] + bh[h];
        }
        return;
    }
    idx -= SETUP_WG;
    if (idx < SETUP_P) {
        const int n = idx >> 10, k = idx & 1023;
        const float v = (n < OMID) ? W1[n * HID + k] : (n == OMID ? W_halt[k] : 0.f);
        P[idx] = f2bf(v);
        if (k == 0) bias_p[n] = (n < OMID) ? b1[n] : (n == OMID ? b_halt[0] : 0.f);
    }
}

extern "C" void kernel_launch(void* const* d_in, const int* in_sizes, int n_in,
                              void* d_out, int out_size, void* d_ws, size_t ws_size,
                              hipStream_t stream) {
    const float* x    = (const float*)d_in[0];
    const float* Wxi  = (const float*)d_in[1];
    const float* bxi  = (const float*)d_in[2];
    const float* Whi  = (const float*)d_in[3];
    const float* bhi  = (const float*)d_in[4];
    const float* Wxf  = (const float*)d_in[5];
    const float* bxf  = (const float*)d_in[6];
    const float* Whf  = (const float*)d_in[7];
    const float* bhf  = (const float*)d_in[8];
    const float* Wxc  = (const float*)d_in[9];
    const float* bxc  = (const float*)d_in[10];
    const float* Whc  = (const float*)d_in[11];
    const float* bhc  = (const float*)d_in[12];
    const float* Wxo  = (const float*)d_in[13];
    const float* bxo  = (const float*)d_in[14];
    const float* Who  = (const float*)d_in[15];
    const float* bho  = (const float*)d_in[16];
    const float* W_halt = (const float*)d_in[17];
    const float* b_halt = (const float*)d_in[18];
    const float* W1   = (const float*)d_in[19];
    const float* b1   = (const float*)d_in[20];
    const float* W2   = (const float*)d_in[21];
    const float* b2   = (const float*)d_in[22];

    char* p = (char*)d_ws;
    auto carve = [&](size_t bytes) { char* r = p; p += (bytes + 255) & ~(size_t)255; return r; };
    short* A0     = (short*)carve((size_t)BATCH * KTOT * 2);
    short* A1     = (short*)carve((size_t)BATCH * KTOT * 2);
    short* Wg     = (short*)carve((size_t)NGATES * KTOT * 2);
    float* bias_g = (float*)carve((size_t)NGATES * 4);
    short* P      = (short*)carve((size_t)NP * HID * 2);
    float* bias_p = (float*)carve((size_t)NP * 4);
    float* cell   = (float*)carve((size_t)BATCH * HID * 4);
    float* p_sum  = (float*)carve((size_t)BATCH * 4);
    int*   ridx0  = (int*)carve((size_t)BATCH * 4);
    int*   ridx1  = (int*)carve((size_t)BATCH * 4);
    int*   cnt    = (int*)carve((size_t)(MAX_ITER + 1) * 4);
    int*   bar    = (int*)carve(256);
    float* outp   = (float*)d_out;

    setup_k<<<(SETUP_TOT + 255) / 256, 256, 0, stream>>>(
        x, Whi, Whf, Whc, Who, Wxi, Wxf, Wxc, Wxo,
        bxi, bhi, bxf, bhf, bxc, bhc, bxo, bho,
        W1, b1, W_halt, b_halt,
        A0, A1, cell, p_sum, ridx0, ridx1, cnt, bar, outp,
        Wg, bias_g, P, bias_p);

    // t=0: state==0 -> x-part only (K=64)
    gates_k<<<dim3(NGATES / TN, 32), 256, 0, stream>>>(
        A0 + HID, Wg + HID, bias_g, IN_DIM, cell, A1, ridx0, cnt, 0);
    midfin_k<<<64, 256, 0, stream>>>(
        A1, P, bias_p, W_halt, W2, b2, outp, p_sum, ridx0, ridx1, cnt, 0);
    // t=1: full batch
    gates_k<<<dim3(NGATES / TN, 32), 256, 0, stream>>>(
        A1, Wg, bias_g, KTOT, cell, A0, ridx1, cnt, 1);
    midfin_k<<<64, 256, 0, stream>>>(
        A0, P, bias_p, W_halt, W2, b2, outp, p_sum, ridx1, ridx0, cnt, 1);
    // t=2: ~half batch
    gates_k<<<dim3(NGATES / TN, 32), 256, 0, stream>>>(
        A0, Wg, bias_g, KTOT, cell, A1, ridx0, cnt, 2);
    // midfin(2) + steps 3..7 in one persistent 64-block kernel
    tail_k<<<TAILB, 256, 0, stream>>>(
        Wg, bias_g, P, bias_p, W_halt, W2, b2,
        A0, A1, cell, outp, p_sum, ridx0, ridx1, cnt, bar);
}

// Round 13
// 457.713 us; speedup vs baseline: 1.7656x; 1.5953x over previous
//
#include <hip/hip_runtime.h>
#include <hip/hip_bf16.h>

#define BATCH 8192
#define IN_DIM 64
#define HID 1024
#define KTOT 1088   // HID + IN_DIM, fused K
#define NGATES 4096 // 4*HID, column c = 64*G + 16*g + q -> gate g of h=16*G+q
#define OMID 128
#define NP 256      // packed P rows (W1 0..127, W_halt 128, zeros)
#define MAX_ITER 8

#define TM 128
#define TN 128
#define TK 64
#define GYD 16      // gates grid y; blocks pair m-tiles (by, by+GYD)
#define TAILB 64    // tail_k blocks: few enough that a device barrier is cheap

typedef __attribute__((ext_vector_type(8))) short short8;
typedef __attribute__((ext_vector_type(4))) float float4v;

__device__ __forceinline__ float bf2f(short s) {
    union { float f; unsigned u; } v; v.u = ((unsigned)(unsigned short)s) << 16; return v.f;
}
__device__ __forceinline__ short f2bf(float f) {
    union { float f; unsigned u; } v; v.f = f;
    unsigned r = v.u + 0x7fff + ((v.u >> 16) & 1);  // round-to-nearest-even
    return (short)(r >> 16);
}
__device__ __forceinline__ float sigmoidf_(float x) {
    float xc = fminf(fmaxf(x, -30.f), 30.f);
    return 1.f / (1.f + __expf(-xc));
}
__device__ __forceinline__ float tanhf_(float x) {
    float xc = fminf(fmaxf(x, -15.f), 15.f);
    float e = __expf(2.f * xc);
    return (e - 1.f) / (e + 1.f);
}
__device__ __forceinline__ int aload(const int* p) {
    return __hip_atomic_load((int*)p, __ATOMIC_RELAXED, __HIP_MEMORY_SCOPE_AGENT);
}
__device__ __forceinline__ void astore(int* p, int v) {
    __hip_atomic_store(p, v, __ATOMIC_RELAXED, __HIP_MEMORY_SCOPE_AGENT);
}

// 64-block generation barrier (R8-verified; R5/R7/R11: ANY wider barrier
// pays 50-100us in cross-XCD L2 invalidate traffic). RELAXED polling by one
// lane per block with s_sleep; fences only at the crossing points.
__device__ __forceinline__ void gbar(int* bar, int phase, int tid) {
    __syncthreads();
    if (tid == 0) {
        __threadfence();
        __hip_atomic_fetch_add(bar, 1, __ATOMIC_ACQ_REL, __HIP_MEMORY_SCOPE_AGENT);
        while (aload(bar) < TAILB * phase)
            __builtin_amdgcn_s_sleep(8);
        __threadfence();
    }
    __syncthreads();
}

// Shared epilogue: fused LSTM cell update for one m-tile's accumulators.
__device__ __forceinline__ void gates_epilogue(
    const float4v (&acc)[4][4], int m0, int bx, int wave, int lane,
    const float* __restrict__ bias_g, float* __restrict__ cell,
    short* __restrict__ Aout, const int* __restrict__ ridx, int n_act)
{
    const int wm = wave & 1, wn = wave >> 1;
    const int colq = lane & 15, q = lane >> 4;
    const int G = bx * 2 + wn;   // 64-col group = 16 hidden units
    const int h = G * 16 + colq;
    const float bi  = bias_g[G * 64 +  0 + colq];
    const float bff = bias_g[G * 64 + 16 + colq];
    const float bc  = bias_g[G * 64 + 32 + colq];
    const float bo  = bias_g[G * 64 + 48 + colq];
#pragma unroll
    for (int i = 0; i < 4; ++i) {
        const int pbase = m0 + wm * 64 + i * 16 + q * 4;
#pragma unroll
        for (int r = 0; r < 4; ++r) {
            const int pos = pbase + r;
            if (pos < n_act) {
                const int row = ridx[pos];
                const float ig = sigmoidf_(acc[i][0][r] + bi);
                const float fg = sigmoidf_(acc[i][1][r] + bff);
                const float cg = tanhf_(acc[i][2][r] + bc);
                const float og = sigmoidf_(acc[i][3][r] + bo);
                const size_t ci = (size_t)row * HID + h;
                const float c = fg * cell[ci] + ig * cg;
                cell[ci] = c;
                Aout[(size_t)row * KTOT + h] = f2bf(og * tanhf_(c));
            }
        }
    }
}

// Gates GEMM with M-TILE PAIRING: each block processes m-tiles (by, by+GYD)
// in ONE k-loop pass — the B k-chunk is staged once and feeds 64 MFMAs per
// barrier pair instead of 32 (R10 A/B: 2 blocks/CU already saturates the
// per-CU staging path, so denser blocks, not more blocks, is the lever).
// LDS 48 KB (Bs + 2xAs); acc[2][4][4] -> ~230 VGPR -> 2 blocks/CU, which
// R10 proved sufficient. LDS XOR swizzle (R2: 0 conflicts) retained.
// t=0 host-special-cased: A,B offset by HID, K=64 (state==0).
__global__ __launch_bounds__(256, 2) void gates_k(
    const short* __restrict__ A, const short* __restrict__ B,
    const float* __restrict__ bias_g, int K,
    float* __restrict__ cell, short* __restrict__ Aout,
    const int* __restrict__ ridx, const int* __restrict__ cnt, int t)
{
    __shared__ short Bs[TN * TK];
    __shared__ short As0[TM * TK];
    __shared__ short As1[TM * TK];
    const int n_act = cnt[t];
    const int tid  = threadIdx.x;
    const int wave = tid >> 6, lane = tid & 63;
    const int wm = wave & 1, wn = wave >> 1;
    const int colq = lane & 15, q = lane >> 4;
    const int lrow8 = lane >> 3;
    const int lk    = (((lane & 7) ^ lrow8) * 8);
    const int n0 = blockIdx.x * TN;

    // k0-invariant LDS read offsets (same for both A tiles)
    int aoff[4][2], boff[4][2];
#pragma unroll
    for (int i = 0; i < 4; ++i) {
        const int Ra = wm * 64 + i * 16 + colq;
        const int Rb = wn * 64 + i * 16 + colq;
#pragma unroll
        for (int c2 = 0; c2 < 2; ++c2) {
            const int C = q + 4 * c2;
            aoff[i][c2] = Ra * TK + ((C ^ (Ra & 7)) << 3);
            boff[i][c2] = Rb * TK + ((C ^ (Rb & 7)) << 3);
        }
    }

    for (int by0 = blockIdx.y; by0 * TM < n_act; by0 += 2 * (int)gridDim.y) {
        const int by1 = by0 + gridDim.y;
        const bool dual = (by1 * TM < n_act);   // block-uniform
        const int m0 = by0 * TM, m1 = by1 * TM;

        float4v acc0[4][4], acc1[4][4];
#pragma unroll
        for (int i = 0; i < 4; ++i)
#pragma unroll
            for (int j = 0; j < 4; ++j) { acc0[i][j] = (float4v)0.f; acc1[i][j] = (float4v)0.f; }

        const short* ga0[4];
        const short* ga1[4];
        const short* gb[4];
#pragma unroll
        for (int it = 0; it < 4; ++it) {
            const int rr = (wave * 4 + it) * 8;
            ga0[it] = A + (size_t)ridx[m0 + rr + lrow8] * KTOT + lk;
            ga1[it] = dual ? A + (size_t)ridx[m1 + rr + lrow8] * KTOT + lk : ga0[it];
            gb[it]  = B + (size_t)(n0 + rr + lrow8) * KTOT + lk;
        }

        for (int k0 = 0; k0 < K; k0 += TK) {
#pragma unroll
            for (int it = 0; it < 4; ++it) {
                const int rr = (wave * 4 + it) * 8;
                __builtin_amdgcn_global_load_lds(
                    (const __attribute__((address_space(1))) void*)gb[it],
                    (__attribute__((address_space(3))) void*)(Bs + rr * TK), 16, 0, 0);
                __builtin_amdgcn_global_load_lds(
                    (const __attribute__((address_space(1))) void*)ga0[it],
                    (__attribute__((address_space(3))) void*)(As0 + rr * TK), 16, 0, 0);
                if (dual)
                    __builtin_amdgcn_global_load_lds(
                        (const __attribute__((address_space(1))) void*)ga1[it],
                        (__attribute__((address_space(3))) void*)(As1 + rr * TK), 16, 0, 0);
                ga0[it] += TK; ga1[it] += TK; gb[it] += TK;
            }
            __syncthreads();
#pragma unroll
            for (int c2 = 0; c2 < 2; ++c2) {
                short8 bf[4], af0[4], af1[4];
#pragma unroll
                for (int i = 0; i < 4; ++i) {
                    bf[i]  = *(const short8*)(Bs  + boff[i][c2]);
                    af0[i] = *(const short8*)(As0 + aoff[i][c2]);
                    af1[i] = *(const short8*)(As1 + aoff[i][c2]);
                }
#pragma unroll
                for (int i = 0; i < 4; ++i)
#pragma unroll
                    for (int j = 0; j < 4; ++j) {
                        acc0[i][j] = __builtin_amdgcn_mfma_f32_16x16x32_bf16(af0[i], bf[j], acc0[i][j], 0, 0, 0);
                        acc1[i][j] = __builtin_amdgcn_mfma_f32_16x16x32_bf16(af1[i], bf[j], acc1[i][j], 0, 0, 0);
                    }
            }
            __syncthreads();
        }

        gates_epilogue(acc0, m0, blockIdx.x, wave, lane, bias_g, cell, Aout, ridx, n_act);
        if (dual)
            gates_epilogue(acc1, m1, blockIdx.x, wave, lane, bias_g, cell, Aout, ridx, n_act);
        __syncthreads();   // protect LDS before next pair
    }
}

// Single-m-tile gates (R10 form) — used only inside tail_k (64 blocks).
__device__ __forceinline__ void gates_tile(
    short* As, short* Bs, int tid,
    const short* __restrict__ A, const short* __restrict__ B,
    const float* __restrict__ bias_g, int K,
    float* __restrict__ cell, short* __restrict__ Aout,
    const int* __restrict__ ridx, int n_act, int m0, int bx)
{
    const int wave = tid >> 6, lane = tid & 63;
    const int wm = wave & 1, wn = wave >> 1;
    const int colq = lane & 15, q = lane >> 4;
    const int lrow8 = lane >> 3;
    const int lk    = (((lane & 7) ^ lrow8) * 8);
    const int n0 = bx * TN;

    int aoff[4][2], boff[4][2];
#pragma unroll
    for (int i = 0; i < 4; ++i) {
        const int Ra = wm * 64 + i * 16 + colq;
        const int Rb = wn * 64 + i * 16 + colq;
#pragma unroll
        for (int c2 = 0; c2 < 2; ++c2) {
            const int C = q + 4 * c2;
            aoff[i][c2] = Ra * TK + ((C ^ (Ra & 7)) << 3);
            boff[i][c2] = Rb * TK + ((C ^ (Rb & 7)) << 3);
        }
    }

    float4v acc[4][4];
#pragma unroll
    for (int i = 0; i < 4; ++i)
#pragma unroll
        for (int j = 0; j < 4; ++j) acc[i][j] = (float4v)0.f;

    const short* ga[4];
    const short* gb[4];
#pragma unroll
    for (int it = 0; it < 4; ++it) {
        const int rr = (wave * 4 + it) * 8;
        ga[it] = A + (size_t)ridx[m0 + rr + lrow8] * KTOT + lk;
        gb[it] = B + (size_t)(n0 + rr + lrow8) * KTOT + lk;
    }

    for (int k0 = 0; k0 < K; k0 += TK) {
#pragma unroll
        for (int it = 0; it < 4; ++it) {
            const int rr = (wave * 4 + it) * 8;
            __builtin_amdgcn_global_load_lds(
                (const __attribute__((address_space(1))) void*)ga[it],
                (__attribute__((address_space(3))) void*)(As + rr * TK), 16, 0, 0);
            __builtin_amdgcn_global_load_lds(
                (const __attribute__((address_space(1))) void*)gb[it],
                (__attribute__((address_space(3))) void*)(Bs + rr * TK), 16, 0, 0);
            ga[it] += TK; gb[it] += TK;
        }
        __syncthreads();
#pragma unroll
        for (int c2 = 0; c2 < 2; ++c2) {
            short8 af[4], bf[4];
#pragma unroll
            for (int i = 0; i < 4; ++i) {
                af[i] = *(const short8*)(As + aoff[i][c2]);
                bf[i] = *(const short8*)(Bs + boff[i][c2]);
            }
#pragma unroll
            for (int i = 0; i < 4; ++i)
#pragma unroll
                for (int j = 0; j < 4; ++j)
                    acc[i][j] = __builtin_amdgcn_mfma_f32_16x16x32_bf16(af[i], bf[j], acc[i][j], 0, 0, 0);
        }
        __syncthreads();
    }

    gates_epilogue(acc, m0, bx, wave, lane, bias_g, cell, Aout, ridx, n_act);
    __syncthreads();   // protect As/Bs before caller's next tile
}

// One 128-row midfin tile: mid GEMM (128 cols = W1, K=HID) + W2-dot via
// shuffle+LDS reduction + halt-dot (state·W_halt fp32) + halting
// bookkeeping. red/hbuf alias As (only touched after the k-loop).
__device__ __forceinline__ void midfin_tile(
    short* As, short* Bs, int tid,
    const short* __restrict__ Anew, const short* __restrict__ P,
    const float* __restrict__ bias_p, const float* __restrict__ W_halt,
    const float* __restrict__ W2, const float* __restrict__ b2,
    float* __restrict__ outp, float* __restrict__ p_sum,
    const int* __restrict__ rprev, int* __restrict__ rnext,
    int* __restrict__ cnt, int t, int m0, int n_act)
{
    const int wave = tid >> 6, lane = tid & 63;
    const int wm = wave & 1, wn = wave >> 1;
    const int colq = lane & 15, q = lane >> 4;
    const int lrow8 = lane >> 3;
    const int lk    = (((lane & 7) ^ lrow8) * 8);

    float4v acc[4][4];
#pragma unroll
    for (int i = 0; i < 4; ++i)
#pragma unroll
        for (int j = 0; j < 4; ++j) acc[i][j] = (float4v)0.f;

    const short* ga[4];
    const short* gb[4];
#pragma unroll
    for (int it = 0; it < 4; ++it) {
        const int rr = (wave * 4 + it) * 8;
        ga[it] = Anew + (size_t)rprev[m0 + rr + lrow8] * KTOT + lk;
        gb[it] = P + (size_t)(rr + lrow8) * HID + lk;
    }
    int aoff[4][2], boff[4][2];
#pragma unroll
    for (int i = 0; i < 4; ++i) {
        const int Ra = wm * 64 + i * 16 + colq;
        const int Rb = wn * 64 + i * 16 + colq;
#pragma unroll
        for (int c2 = 0; c2 < 2; ++c2) {
            const int C = q + 4 * c2;
            aoff[i][c2] = Ra * TK + ((C ^ (Ra & 7)) << 3);
            boff[i][c2] = Rb * TK + ((C ^ (Rb & 7)) << 3);
        }
    }

    for (int k0 = 0; k0 < HID; k0 += TK) {
#pragma unroll
        for (int it = 0; it < 4; ++it) {
            const int rr = (wave * 4 + it) * 8;
            __builtin_amdgcn_global_load_lds(
                (const __attribute__((address_space(1))) void*)ga[it],
                (__attribute__((address_space(3))) void*)(As + rr * TK), 16, 0, 0);
            __builtin_amdgcn_global_load_lds(
                (const __attribute__((address_space(1))) void*)gb[it],
                (__attribute__((address_space(3))) void*)(Bs + rr * TK), 16, 0, 0);
            ga[it] += TK; gb[it] += TK;
        }
        __syncthreads();
#pragma unroll
        for (int c2 = 0; c2 < 2; ++c2) {
            short8 af[4], bf[4];
#pragma unroll
            for (int i = 0; i < 4; ++i) {
                af[i] = *(const short8*)(As + aoff[i][c2]);
                bf[i] = *(const short8*)(Bs + boff[i][c2]);
            }
#pragma unroll
            for (int i = 0; i < 4; ++i)
#pragma unroll
                for (int j = 0; j < 4; ++j)
                    acc[i][j] = __builtin_amdgcn_mfma_f32_16x16x32_bf16(af[i], bf[j], acc[i][j], 0, 0, 0);
        }
        __syncthreads();
    }

    // aliases over As (k-loop done; last barrier above protects)
    float* red  = (float*)As;           // 256 floats: [wn][wm][i][q][r]
    float* hbuf = ((float*)As) + 256;   // 128 floats

    // halt-dot: per row, state · W_halt
    for (int s = 0; s < 32; ++s) {
        const int lr = wave * 32 + s;
        const int row = rprev[m0 + lr];
        const short* Ar = Anew + (size_t)row * KTOT + lane * 16;
        const short8 v0 = *(const short8*)Ar;
        const short8 v1 = *(const short8*)(Ar + 8);
        const float* Wh = W_halt + lane * 16;
        float hv = 0.f;
#pragma unroll
        for (int e = 0; e < 8; ++e) hv += bf2f(v0[e]) * Wh[e];
#pragma unroll
        for (int e = 0; e < 8; ++e) hv += bf2f(v1[e]) * Wh[8 + e];
#pragma unroll
        for (int o = 32; o > 0; o >>= 1) hv += __shfl_down(hv, o);
        if (lane == 0) hbuf[lr] = hv;
    }

    // relu + W2-dot, reduce over cols
    float pr[4][4];
#pragma unroll
    for (int i = 0; i < 4; ++i)
#pragma unroll
        for (int r = 0; r < 4; ++r) pr[i][r] = 0.f;
#pragma unroll
    for (int j = 0; j < 4; ++j) {
        const int col = wn * 64 + j * 16 + colq;
        const float b = bias_p[col];
        const float w2 = W2[col];
#pragma unroll
        for (int i = 0; i < 4; ++i)
#pragma unroll
            for (int r = 0; r < 4; ++r)
                pr[i][r] += fmaxf(acc[i][j][r] + b, 0.f) * w2;
    }
#pragma unroll
    for (int i = 0; i < 4; ++i)
#pragma unroll
        for (int r = 0; r < 4; ++r) {
            float v = pr[i][r];
            v += __shfl_down(v, 8, 16);
            v += __shfl_down(v, 4, 16);
            v += __shfl_down(v, 2, 16);
            v += __shfl_down(v, 1, 16);
            if (colq == 0)
                red[((((wn * 2) + wm) * 4 + i) * 4 + q) * 4 + r] = v;
        }
    __syncthreads();

    // finalize: one thread per row
    if (tid < TM) {
        const int pos = m0 + tid;
        if (pos < n_act) {
            const int lwm = tid >> 6, i = (tid >> 4) & 3, lq = (tid >> 2) & 3, r = tid & 3;
            const float odot = red[((lwm * 4 + i) * 4 + lq) * 4 + r]
                             + red[(((2 + lwm) * 4 + i) * 4 + lq) * 4 + r];
            const int row = rprev[pos];
            const float ov = sigmoidf_(odot + b2[0]);
            const float h  = sigmoidf_(hbuf[tid] + bias_p[OMID]);
            const float ps = p_sum[row];
            const float pn = ps + h;
            const bool fin = (pn >= 1.f - 1e-3f) || (t == MAX_ITER - 1);
            const float halt = fin ? (1.f - ps) : h;
            outp[row] += ov * halt;
            p_sum[row] = fin ? 1.f : pn;
            if (!fin) {
                const int d = atomicAdd(&cnt[t + 1], 1);
                astore(&rnext[d], row);
            }
        }
    }
    __syncthreads();   // protect As/Bs aliases before caller reuses LDS
}

// Standalone midfin dispatch (steps 0..1).
__global__ __launch_bounds__(256) void midfin_k(
    const short* __restrict__ Anew, const short* __restrict__ P,
    const float* __restrict__ bias_p, const float* __restrict__ W_halt,
    const float* __restrict__ W2, const float* __restrict__ b2,
    float* __restrict__ outp, float* __restrict__ p_sum,
    const int* __restrict__ rprev, int* __restrict__ rnext,
    int* __restrict__ cnt, int t)
{
    __shared__ short As[TM * TK];
    __shared__ short Bs[TN * TK];
    const int n_act = cnt[t];
    for (int tile = blockIdx.x; tile * TM < n_act; tile += gridDim.x)
        midfin_tile(As, Bs, threadIdx.x, Anew, P, bias_p, W_halt, W2, b2,
                    outp, p_sum, rprev, rnext, cnt, t, tile * TM, n_act);
}

// Persistent 64-block tail: midfin(2) + steps 3..7 (gates+midfin) with
// in-kernel barriers. For this data cnt[3]==0 so the generic loop exits
// after midfin(2)+1 barrier; full loop retained for arbitrary data.
__global__ __launch_bounds__(256) void tail_k(
    const short* __restrict__ Wg, const float* __restrict__ bias_g,
    const short* __restrict__ P, const float* __restrict__ bias_p,
    const float* __restrict__ W_halt, const float* __restrict__ W2,
    const float* __restrict__ b2,
    short* __restrict__ A0, short* __restrict__ A1,
    float* __restrict__ cell, float* __restrict__ outp,
    float* __restrict__ p_sum,
    int* __restrict__ ridx0, int* __restrict__ ridx1,
    int* __restrict__ cnt, int* __restrict__ bar)
{
    __shared__ short As[TM * TK];
    __shared__ short Bs[TN * TK];
    const int tid = threadIdx.x;
    int phase = 0;
    int t = 2;
    while (true) {
        short* Anew = (t & 1) ? A0 : A1;        // state written by gates(t)
        const int* rprev = (t & 1) ? ridx1 : ridx0;  // L_t
        int* rnext = (t & 1) ? ridx0 : ridx1;        // L_{t+1}
        const int n = aload(&cnt[t]);
        for (int tile = blockIdx.x; tile * TM < n; tile += gridDim.x)
            midfin_tile(As, Bs, tid, Anew, P, bias_p, W_halt, W2, b2,
                        outp, p_sum, rprev, rnext, cnt, t, tile * TM, n);
        if (t == MAX_ITER - 1) break;
        ++phase; gbar(bar, phase, tid);          // publish cnt[t+1], ridx, p_sum
        const int n1 = aload(&cnt[t + 1]);
        if (n1 == 0) break;                      // uniform across blocks
        {
            short* Aot = (t & 1) ? A1 : A0;
            const int ntiles = ((n1 + TM - 1) / TM) * (NGATES / TN);
            for (int e = blockIdx.x; e < ntiles; e += gridDim.x)
                gates_tile(As, Bs, tid, Anew, Wg, bias_g, KTOT, cell, Aot,
                           rnext, n1, (e >> 5) * TM, e & 31);
        }
        ++phase; gbar(bar, phase, tid);          // publish Aout, cell
        ++t;
    }
}

// one dispatch for all setup: weight packing + A/cell/bookkeeping init
#define SETUP_INIT  (BATCH * KTOT)
#define SETUP_WG    (NGATES * KTOT)
#define SETUP_P     (NP * HID)
#define SETUP_TOT   (SETUP_INIT + SETUP_WG + SETUP_P)
__global__ __launch_bounds__(256) void setup_k(
    const float* __restrict__ x,
    const float* __restrict__ Whi, const float* __restrict__ Whf,
    const float* __restrict__ Whc, const float* __restrict__ Who,
    const float* __restrict__ Wxi, const float* __restrict__ Wxf,
    const float* __restrict__ Wxc, const float* __restrict__ Wxo,
    const float* __restrict__ bxi, const float* __restrict__ bhi,
    const float* __restrict__ bxf, const float* __restrict__ bhf,
    const float* __restrict__ bxc, const float* __restrict__ bhc,
    const float* __restrict__ bxo, const float* __restrict__ bho,
    const float* __restrict__ W1, const float* __restrict__ b1,
    const float* __restrict__ W_halt, const float* __restrict__ b_halt,
    short* __restrict__ A0, short* __restrict__ A1,
    float* __restrict__ cell, float* __restrict__ p_sum,
    int* __restrict__ ridx0, int* __restrict__ ridx1, int* __restrict__ cnt,
    int* __restrict__ bar, float* __restrict__ outp,
    short* __restrict__ Wg, float* __restrict__ bias_g,
    short* __restrict__ P, float* __restrict__ bias_p)
{
    int idx = blockIdx.x * 256 + threadIdx.x;
    if (idx < SETUP_INIT) {
        const int row = idx / KTOT, k = idx - row * KTOT;
        const short v = (k < HID) ? (short)0 : f2bf(x[row * IN_DIM + (k - HID)]);
        A0[idx] = v;
        A1[idx] = v;   // x cols iteration-invariant; state part overwritten each step
        if (k < HID) cell[(size_t)row * HID + k] = 0.f;
        if (k == 0) {
            p_sum[row] = 0.f;
            outp[row] = 0.f;
            ridx0[row] = row;   // step 0: identity compaction
            ridx1[row] = 0;     // in-range dummies for padded tile reads
        }
        if (row == 0 && k <= MAX_ITER) cnt[k] = (k == 0) ? BATCH : 0;
        if (row == 1 && k == 0) bar[0] = 0;
        return;
    }
    idx -= SETUP_INIT;
    if (idx < SETUP_WG) {
        const int n = idx / KTOT, k = idx - n * KTOT;
        // interleaved layout: n = 64*G + 16*g + q  ->  gate g of hidden h=16*G+q
        const int G = n >> 6, g = (n >> 4) & 3, q = n & 15;
        const int h = G * 16 + q;
        const float* Wh = (g == 0) ? Whi : (g == 1) ? Whf : (g == 2) ? Whc : Who;
        const float* Wx = (g == 0) ? Wxi : (g == 1) ? Wxf : (g == 2) ? Wxc : Wxo;
        const float v = (k < HID) ? Wh[h * HID + k] : Wx[h * IN_DIM + (k - HID)];
        Wg[idx] = f2bf(v);
        if (k == 0) {
            const float* bx = (g == 0) ? bxi : (g == 1) ? bxf : (g == 2) ? bxc : bxo;
            const float* bh = (g == 0) ? bhi : (g == 1) ? bhf : (g == 2) ? bhc : bho;
            bias_g[n] = bx[h] + bh[h];
        }
        return;
    }
    idx -= SETUP_WG;
    if (idx < SETUP_P) {
        const int n = idx >> 10, k = idx & 1023;
        const float v = (n < OMID) ? W1[n * HID + k] : (n == OMID ? W_halt[k] : 0.f);
        P[idx] = f2bf(v);
        if (k == 0) bias_p[n] = (n < OMID) ? b1[n] : (n == OMID ? b_halt[0] : 0.f);
    }
}

extern "C" void kernel_launch(void* const* d_in, const int* in_sizes, int n_in,
                              void* d_out, int out_size, void* d_ws, size_t ws_size,
                              hipStream_t stream) {
    const float* x    = (const float*)d_in[0];
    const float* Wxi  = (const float*)d_in[1];
    const float* bxi  = (const float*)d_in[2];
    const float* Whi  = (const float*)d_in[3];
    const float* bhi  = (const float*)d_in[4];
    const float* Wxf  = (const float*)d_in[5];
    const float* bxf  = (const float*)d_in[6];
    const float* Whf  = (const float*)d_in[7];
    const float* bhf  = (const float*)d_in[8];
    const float* Wxc  = (const float*)d_in[9];
    const float* bxc  = (const float*)d_in[10];
    const float* Whc  = (const float*)d_in[11];
    const float* bhc  = (const float*)d_in[12];
    const float* Wxo  = (const float*)d_in[13];
    const float* bxo  = (const float*)d_in[14];
    const float* Who  = (const float*)d_in[15];
    const float* bho  = (const float*)d_in[16];
    const float* W_halt = (const float*)d_in[17];
    const float* b_halt = (const float*)d_in[18];
    const float* W1   = (const float*)d_in[19];
    const float* b1   = (const float*)d_in[20];
    const float* W2   = (const float*)d_in[21];
    const float* b2   = (const float*)d_in[22];

    char* p = (char*)d_ws;
    auto carve = [&](size_t bytes) { char* r = p; p += (bytes + 255) & ~(size_t)255; return r; };
    short* A0     = (short*)carve((size_t)BATCH * KTOT * 2);
    short* A1     = (short*)carve((size_t)BATCH * KTOT * 2);
    short* Wg     = (short*)carve((size_t)NGATES * KTOT * 2);
    float* bias_g = (float*)carve((size_t)NGATES * 4);
    short* P      = (short*)carve((size_t)NP * HID * 2);
    float* bias_p = (float*)carve((size_t)NP * 4);
    float* cell   = (float*)carve((size_t)BATCH * HID * 4);
    float* p_sum  = (float*)carve((size_t)BATCH * 4);
    int*   ridx0  = (int*)carve((size_t)BATCH * 4);
    int*   ridx1  = (int*)carve((size_t)BATCH * 4);
    int*   cnt    = (int*)carve((size_t)(MAX_ITER + 1) * 4);
    int*   bar    = (int*)carve(256);
    float* outp   = (float*)d_out;

    setup_k<<<(SETUP_TOT + 255) / 256, 256, 0, stream>>>(
        x, Whi, Whf, Whc, Who, Wxi, Wxf, Wxc, Wxo,
        bxi, bhi, bxf, bhf, bxc, bhc, bxo, bho,
        W1, b1, W_halt, b_halt,
        A0, A1, cell, p_sum, ridx0, ridx1, cnt, bar, outp,
        Wg, bias_g, P, bias_p);

    // t=0: state==0 -> x-part only (K=64)
    gates_k<<<dim3(NGATES / TN, GYD), 256, 0, stream>>>(
        A0 + HID, Wg + HID, bias_g, IN_DIM, cell, A1, ridx0, cnt, 0);
    midfin_k<<<64, 256, 0, stream>>>(
        A1, P, bias_p, W_halt, W2, b2, outp, p_sum, ridx0, ridx1, cnt, 0);
    // t=1: full batch (64 m-tiles -> 2 dual passes/block)
    gates_k<<<dim3(NGATES / TN, GYD), 256, 0, stream>>>(
        A1, Wg, bias_g, KTOT, cell, A0, ridx1, cnt, 1);
    midfin_k<<<64, 256, 0, stream>>>(
        A0, P, bias_p, W_halt, W2, b2, outp, p_sum, ridx1, ridx0, cnt, 1);
    // t=2: ~half batch (32 m-tiles -> exactly 1 dual pass/block)
    gates_k<<<dim3(NGATES / TN, GYD), 256, 0, stream>>>(
        A0, Wg, bias_g, KTOT, cell, A1, ridx0, cnt, 2);
    // midfin(2) + steps 3..7 in one persistent 64-block kernel
    tail_k<<<TAILB, 256, 0, stream>>>(
        Wg, bias_g, P, bias_p, W_halt, W2, b2,
        A0, A1, cell, outp, p_sum, ridx0, ridx1, cnt, bar);
}

// Round 14
// 433.625 us; speedup vs baseline: 1.8637x; 1.0556x over previous
//
#include <hip/hip_runtime.h>
#include <hip/hip_bf16.h>

#define BATCH 8192
#define IN_DIM 64
#define HID 1024
#define KTOT 1088   // HID + IN_DIM (fused K; weights laid out [n][KTOT])
#define NGATES 4096 // 4*HID, column c = 64*G + 16*g + q -> gate g of h=16*G+q
#define OMID 128
#define NP 256      // packed P rows (W1 0..127, W_halt 128, zeros)
#define MAX_ITER 8

#define TM 128
#define TN 128
#define TK 64
#define GYD 16      // gates grid y; blocks pair m-tiles (by, by+GYD)
#define TAILB 64    // tail_k blocks: few enough that a device barrier is cheap

typedef __attribute__((ext_vector_type(8))) short short8;
typedef __attribute__((ext_vector_type(4))) float float4v;

__device__ __forceinline__ float bf2f(short s) {
    union { float f; unsigned u; } v; v.u = ((unsigned)(unsigned short)s) << 16; return v.f;
}
__device__ __forceinline__ short f2bf(float f) {
    union { float f; unsigned u; } v; v.f = f;
    unsigned r = v.u + 0x7fff + ((v.u >> 16) & 1);  // round-to-nearest-even
    return (short)(r >> 16);
}
__device__ __forceinline__ float sigmoidf_(float x) {
    float xc = fminf(fmaxf(x, -30.f), 30.f);
    return 1.f / (1.f + __expf(-xc));
}
__device__ __forceinline__ float tanhf_(float x) {
    float xc = fminf(fmaxf(x, -15.f), 15.f);
    float e = __expf(2.f * xc);
    return (e - 1.f) / (e + 1.f);
}
__device__ __forceinline__ int aload(const int* p) {
    return __hip_atomic_load((int*)p, __ATOMIC_RELAXED, __HIP_MEMORY_SCOPE_AGENT);
}
__device__ __forceinline__ void astore(int* p, int v) {
    __hip_atomic_store(p, v, __ATOMIC_RELAXED, __HIP_MEMORY_SCOPE_AGENT);
}

// 64-block generation barrier (R8-verified; R5/R7/R11: ANY wider barrier
// pays 50-100us in cross-XCD L2 invalidate traffic). RELAXED polling by one
// lane per block with s_sleep; fences only at the crossing points.
__device__ __forceinline__ void gbar(int* bar, int phase, int tid) {
    __syncthreads();
    if (tid == 0) {
        __threadfence();
        __hip_atomic_fetch_add(bar, 1, __ATOMIC_ACQ_REL, __HIP_MEMORY_SCOPE_AGENT);
        while (aload(bar) < TAILB * phase)
            __builtin_amdgcn_s_sleep(8);
        __threadfence();
    }
    __syncthreads();
}

// Shared epilogue: fused LSTM cell update for one m-tile's accumulators.
// first=1 (t==0): cell is write-only (c = i*cg == f*0 + i*cg bit-exactly),
// so cell never needs zero-init and t=0 skips the 33.6MB cell read.
__device__ __forceinline__ void gates_epilogue(
    const float4v (&acc)[4][4], int m0, int bx, int wave, int lane, int first,
    const float* __restrict__ bias_g, float* __restrict__ cell,
    short* __restrict__ Sout, const int* __restrict__ ridx, int n_act)
{
    const int wm = wave & 1, wn = wave >> 1;
    const int colq = lane & 15, q = lane >> 4;
    const int G = bx * 2 + wn;   // 64-col group = 16 hidden units
    const int h = G * 16 + colq;
    const float bi  = bias_g[G * 64 +  0 + colq];
    const float bff = bias_g[G * 64 + 16 + colq];
    const float bc  = bias_g[G * 64 + 32 + colq];
    const float bo  = bias_g[G * 64 + 48 + colq];
#pragma unroll
    for (int i = 0; i < 4; ++i) {
        const int pbase = m0 + wm * 64 + i * 16 + q * 4;
#pragma unroll
        for (int r = 0; r < 4; ++r) {
            const int pos = pbase + r;
            if (pos < n_act) {
                const int row = ridx[pos];
                const float ig = sigmoidf_(acc[i][0][r] + bi);
                const float fg = sigmoidf_(acc[i][1][r] + bff);
                const float cg = tanhf_(acc[i][2][r] + bc);
                const float og = sigmoidf_(acc[i][3][r] + bo);
                const size_t ci = (size_t)row * HID + h;
                const float c = first ? (ig * cg) : (fg * cell[ci] + ig * cg);
                cell[ci] = c;
                Sout[(size_t)row * HID + h] = f2bf(og * tanhf_(c));
            }
        }
    }
}

// Gates GEMM with M-TILE PAIRING (R13-verified: g1 146->103us; denser
// blocks, not more blocks — R10 A/B showed 2 blocks/CU saturates staging).
// SPLIT A LAYOUT: state S[row][HID] (never initialized — t=0 writes all
// entries before any read) + shared XB[row][64] (x, iteration-invariant);
// the k-loop's final chunk sources from XB (uniform branch). Weights stay
// [n][KTOT] with x-part at cols 1024.. (B pre-offset +HID for t=0).
// LDS XOR swizzle (R2: 0 conflicts) retained.
__global__ __launch_bounds__(256, 2) void gates_k(
    const short* __restrict__ S, const short* __restrict__ XB,
    const short* __restrict__ B,
    const float* __restrict__ bias_g, int nK, int hidK, int first,
    float* __restrict__ cell, short* __restrict__ Sout,
    const int* __restrict__ ridx, const int* __restrict__ cnt, int t)
{
    __shared__ short Bs[TN * TK];
    __shared__ short As0[TM * TK];
    __shared__ short As1[TM * TK];
    const int n_act = cnt[t];
    const int tid  = threadIdx.x;
    const int wave = tid >> 6, lane = tid & 63;
    const int wm = wave & 1, wn = wave >> 1;
    const int colq = lane & 15, q = lane >> 4;
    const int lrow8 = lane >> 3;
    const int lk    = (((lane & 7) ^ lrow8) * 8);
    const int n0 = blockIdx.x * TN;

    // k0-invariant LDS read offsets (same for both A tiles)
    int aoff[4][2], boff[4][2];
#pragma unroll
    for (int i = 0; i < 4; ++i) {
        const int Ra = wm * 64 + i * 16 + colq;
        const int Rb = wn * 64 + i * 16 + colq;
#pragma unroll
        for (int c2 = 0; c2 < 2; ++c2) {
            const int C = q + 4 * c2;
            aoff[i][c2] = Ra * TK + ((C ^ (Ra & 7)) << 3);
            boff[i][c2] = Rb * TK + ((C ^ (Rb & 7)) << 3);
        }
    }

    for (int by0 = blockIdx.y; by0 * TM < n_act; by0 += 2 * (int)gridDim.y) {
        const int by1 = by0 + gridDim.y;
        const bool dual = (by1 * TM < n_act);   // block-uniform
        const int m0 = by0 * TM, m1 = by1 * TM;

        float4v acc0[4][4], acc1[4][4];
#pragma unroll
        for (int i = 0; i < 4; ++i)
#pragma unroll
            for (int j = 0; j < 4; ++j) { acc0[i][j] = (float4v)0.f; acc1[i][j] = (float4v)0.f; }

        const short* gaS0[4];
        const short* gaS1[4];
        const short* gaX0[4];
        const short* gaX1[4];
        const short* gb[4];
#pragma unroll
        for (int it = 0; it < 4; ++it) {
            const int rr = (wave * 4 + it) * 8;
            const int r0 = ridx[m0 + rr + lrow8];
            const int r1 = dual ? ridx[m1 + rr + lrow8] : r0;
            gaS0[it] = S + (size_t)r0 * HID + lk;
            gaS1[it] = S + (size_t)r1 * HID + lk;
            gaX0[it] = XB + (size_t)r0 * IN_DIM + lk;
            gaX1[it] = XB + (size_t)r1 * IN_DIM + lk;
            gb[it]   = B + (size_t)(n0 + rr + lrow8) * KTOT + lk;
        }

        for (int ki = 0; ki < nK; ++ki) {
            const bool fromS = (ki * TK < hidK);   // kernel-uniform branch
#pragma unroll
            for (int it = 0; it < 4; ++it) {
                const int rr = (wave * 4 + it) * 8;
                __builtin_amdgcn_global_load_lds(
                    (const __attribute__((address_space(1))) void*)gb[it],
                    (__attribute__((address_space(3))) void*)(Bs + rr * TK), 16, 0, 0);
                const short* a0 = fromS ? gaS0[it] : gaX0[it];
                __builtin_amdgcn_global_load_lds(
                    (const __attribute__((address_space(1))) void*)a0,
                    (__attribute__((address_space(3))) void*)(As0 + rr * TK), 16, 0, 0);
                if (dual) {
                    const short* a1 = fromS ? gaS1[it] : gaX1[it];
                    __builtin_amdgcn_global_load_lds(
                        (const __attribute__((address_space(1))) void*)a1,
                        (__attribute__((address_space(3))) void*)(As1 + rr * TK), 16, 0, 0);
                }
                gaS0[it] += TK; gaS1[it] += TK; gb[it] += TK;
            }
            __syncthreads();
#pragma unroll
            for (int c2 = 0; c2 < 2; ++c2) {
                short8 bf[4], af0[4], af1[4];
#pragma unroll
                for (int i = 0; i < 4; ++i) {
                    bf[i]  = *(const short8*)(Bs  + boff[i][c2]);
                    af0[i] = *(const short8*)(As0 + aoff[i][c2]);
                    af1[i] = *(const short8*)(As1 + aoff[i][c2]);
                }
#pragma unroll
                for (int i = 0; i < 4; ++i)
#pragma unroll
                    for (int j = 0; j < 4; ++j) {
                        acc0[i][j] = __builtin_amdgcn_mfma_f32_16x16x32_bf16(af0[i], bf[j], acc0[i][j], 0, 0, 0);
                        acc1[i][j] = __builtin_amdgcn_mfma_f32_16x16x32_bf16(af1[i], bf[j], acc1[i][j], 0, 0, 0);
                    }
            }
            __syncthreads();
        }

        gates_epilogue(acc0, m0, blockIdx.x, wave, lane, first, bias_g, cell, Sout, ridx, n_act);
        if (dual)
            gates_epilogue(acc1, m1, blockIdx.x, wave, lane, first, bias_g, cell, Sout, ridx, n_act);
        __syncthreads();   // protect LDS before next pair
    }
}

// Single-m-tile gates (R10 form, split-A) — used only inside tail_k.
__device__ __forceinline__ void gates_tile(
    short* As, short* Bs, int tid,
    const short* __restrict__ S, const short* __restrict__ XB,
    const short* __restrict__ B,
    const float* __restrict__ bias_g,
    float* __restrict__ cell, short* __restrict__ Sout,
    const int* __restrict__ ridx, int n_act, int m0, int bx)
{
    const int wave = tid >> 6, lane = tid & 63;
    const int wm = wave & 1, wn = wave >> 1;
    const int colq = lane & 15, q = lane >> 4;
    const int lrow8 = lane >> 3;
    const int lk    = (((lane & 7) ^ lrow8) * 8);
    const int n0 = bx * TN;

    int aoff[4][2], boff[4][2];
#pragma unroll
    for (int i = 0; i < 4; ++i) {
        const int Ra = wm * 64 + i * 16 + colq;
        const int Rb = wn * 64 + i * 16 + colq;
#pragma unroll
        for (int c2 = 0; c2 < 2; ++c2) {
            const int C = q + 4 * c2;
            aoff[i][c2] = Ra * TK + ((C ^ (Ra & 7)) << 3);
            boff[i][c2] = Rb * TK + ((C ^ (Rb & 7)) << 3);
        }
    }

    float4v acc[4][4];
#pragma unroll
    for (int i = 0; i < 4; ++i)
#pragma unroll
        for (int j = 0; j < 4; ++j) acc[i][j] = (float4v)0.f;

    const short* gaS[4];
    const short* gaX[4];
    const short* gb[4];
#pragma unroll
    for (int it = 0; it < 4; ++it) {
        const int rr = (wave * 4 + it) * 8;
        const int r0 = ridx[m0 + rr + lrow8];
        gaS[it] = S + (size_t)r0 * HID + lk;
        gaX[it] = XB + (size_t)r0 * IN_DIM + lk;
        gb[it]  = B + (size_t)(n0 + rr + lrow8) * KTOT + lk;
    }

    for (int ki = 0; ki < KTOT / TK; ++ki) {
        const bool fromS = (ki * TK < HID);
#pragma unroll
        for (int it = 0; it < 4; ++it) {
            const int rr = (wave * 4 + it) * 8;
            const short* a0 = fromS ? gaS[it] : gaX[it];
            __builtin_amdgcn_global_load_lds(
                (const __attribute__((address_space(1))) void*)a0,
                (__attribute__((address_space(3))) void*)(As + rr * TK), 16, 0, 0);
            __builtin_amdgcn_global_load_lds(
                (const __attribute__((address_space(1))) void*)gb[it],
                (__attribute__((address_space(3))) void*)(Bs + rr * TK), 16, 0, 0);
            gaS[it] += TK; gb[it] += TK;
        }
        __syncthreads();
#pragma unroll
        for (int c2 = 0; c2 < 2; ++c2) {
            short8 af[4], bf[4];
#pragma unroll
            for (int i = 0; i < 4; ++i) {
                af[i] = *(const short8*)(As + aoff[i][c2]);
                bf[i] = *(const short8*)(Bs + boff[i][c2]);
            }
#pragma unroll
            for (int i = 0; i < 4; ++i)
#pragma unroll
                for (int j = 0; j < 4; ++j)
                    acc[i][j] = __builtin_amdgcn_mfma_f32_16x16x32_bf16(af[i], bf[j], acc[i][j], 0, 0, 0);
        }
        __syncthreads();
    }

    gates_epilogue(acc, m0, bx, wave, lane, 0, bias_g, cell, Sout, ridx, n_act);
    __syncthreads();   // protect As/Bs before caller's next tile
}

// One 128-row midfin tile: mid GEMM (128 cols = W1, K=HID over state only)
// + W2-dot via shuffle+LDS reduction + halt-dot (state·W_halt fp32) +
// halting bookkeeping. red/hbuf alias As (only touched after the k-loop).
__device__ __forceinline__ void midfin_tile(
    short* As, short* Bs, int tid,
    const short* __restrict__ Snew, const short* __restrict__ P,
    const float* __restrict__ bias_p, const float* __restrict__ W_halt,
    const float* __restrict__ W2, const float* __restrict__ b2,
    float* __restrict__ outp, float* __restrict__ p_sum,
    const int* __restrict__ rprev, int* __restrict__ rnext,
    int* __restrict__ cnt, int t, int m0, int n_act)
{
    const int wave = tid >> 6, lane = tid & 63;
    const int wm = wave & 1, wn = wave >> 1;
    const int colq = lane & 15, q = lane >> 4;
    const int lrow8 = lane >> 3;
    const int lk    = (((lane & 7) ^ lrow8) * 8);

    float4v acc[4][4];
#pragma unroll
    for (int i = 0; i < 4; ++i)
#pragma unroll
        for (int j = 0; j < 4; ++j) acc[i][j] = (float4v)0.f;

    const short* ga[4];
    const short* gb[4];
#pragma unroll
    for (int it = 0; it < 4; ++it) {
        const int rr = (wave * 4 + it) * 8;
        ga[it] = Snew + (size_t)rprev[m0 + rr + lrow8] * HID + lk;
        gb[it] = P + (size_t)(rr + lrow8) * HID + lk;
    }
    int aoff[4][2], boff[4][2];
#pragma unroll
    for (int i = 0; i < 4; ++i) {
        const int Ra = wm * 64 + i * 16 + colq;
        const int Rb = wn * 64 + i * 16 + colq;
#pragma unroll
        for (int c2 = 0; c2 < 2; ++c2) {
            const int C = q + 4 * c2;
            aoff[i][c2] = Ra * TK + ((C ^ (Ra & 7)) << 3);
            boff[i][c2] = Rb * TK + ((C ^ (Rb & 7)) << 3);
        }
    }

    for (int k0 = 0; k0 < HID; k0 += TK) {
#pragma unroll
        for (int it = 0; it < 4; ++it) {
            const int rr = (wave * 4 + it) * 8;
            __builtin_amdgcn_global_load_lds(
                (const __attribute__((address_space(1))) void*)ga[it],
                (__attribute__((address_space(3))) void*)(As + rr * TK), 16, 0, 0);
            __builtin_amdgcn_global_load_lds(
                (const __attribute__((address_space(1))) void*)gb[it],
                (__attribute__((address_space(3))) void*)(Bs + rr * TK), 16, 0, 0);
            ga[it] += TK; gb[it] += TK;
        }
        __syncthreads();
#pragma unroll
        for (int c2 = 0; c2 < 2; ++c2) {
            short8 af[4], bf[4];
#pragma unroll
            for (int i = 0; i < 4; ++i) {
                af[i] = *(const short8*)(As + aoff[i][c2]);
                bf[i] = *(const short8*)(Bs + boff[i][c2]);
            }
#pragma unroll
            for (int i = 0; i < 4; ++i)
#pragma unroll
                for (int j = 0; j < 4; ++j)
                    acc[i][j] = __builtin_amdgcn_mfma_f32_16x16x32_bf16(af[i], bf[j], acc[i][j], 0, 0, 0);
        }
        __syncthreads();
    }

    // aliases over As (k-loop done; last barrier above protects)
    float* red  = (float*)As;           // 256 floats: [wn][wm][i][q][r]
    float* hbuf = ((float*)As) + 256;   // 128 floats

    // halt-dot: per row, state · W_halt
    for (int s = 0; s < 32; ++s) {
        const int lr = wave * 32 + s;
        const int row = rprev[m0 + lr];
        const short* Ar = Snew + (size_t)row * HID + lane * 16;
        const short8 v0 = *(const short8*)Ar;
        const short8 v1 = *(const short8*)(Ar + 8);
        const float* Wh = W_halt + lane * 16;
        float hv = 0.f;
#pragma unroll
        for (int e = 0; e < 8; ++e) hv += bf2f(v0[e]) * Wh[e];
#pragma unroll
        for (int e = 0; e < 8; ++e) hv += bf2f(v1[e]) * Wh[8 + e];
#pragma unroll
        for (int o = 32; o > 0; o >>= 1) hv += __shfl_down(hv, o);
        if (lane == 0) hbuf[lr] = hv;
    }

    // relu + W2-dot, reduce over cols
    float pr[4][4];
#pragma unroll
    for (int i = 0; i < 4; ++i)
#pragma unroll
        for (int r = 0; r < 4; ++r) pr[i][r] = 0.f;
#pragma unroll
    for (int j = 0; j < 4; ++j) {
        const int col = wn * 64 + j * 16 + colq;
        const float b = bias_p[col];
        const float w2 = W2[col];
#pragma unroll
        for (int i = 0; i < 4; ++i)
#pragma unroll
            for (int r = 0; r < 4; ++r)
                pr[i][r] += fmaxf(acc[i][j][r] + b, 0.f) * w2;
    }
#pragma unroll
    for (int i = 0; i < 4; ++i)
#pragma unroll
        for (int r = 0; r < 4; ++r) {
            float v = pr[i][r];
            v += __shfl_down(v, 8, 16);
            v += __shfl_down(v, 4, 16);
            v += __shfl_down(v, 2, 16);
            v += __shfl_down(v, 1, 16);
            if (colq == 0)
                red[((((wn * 2) + wm) * 4 + i) * 4 + q) * 4 + r] = v;
        }
    __syncthreads();

    // finalize: one thread per row
    if (tid < TM) {
        const int pos = m0 + tid;
        if (pos < n_act) {
            const int lwm = tid >> 6, i = (tid >> 4) & 3, lq = (tid >> 2) & 3, r = tid & 3;
            const float odot = red[((lwm * 4 + i) * 4 + lq) * 4 + r]
                             + red[(((2 + lwm) * 4 + i) * 4 + lq) * 4 + r];
            const int row = rprev[pos];
            const float ov = sigmoidf_(odot + b2[0]);
            const float h  = sigmoidf_(hbuf[tid] + bias_p[OMID]);
            const float ps = p_sum[row];
            const float pn = ps + h;
            const bool fin = (pn >= 1.f - 1e-3f) || (t == MAX_ITER - 1);
            const float halt = fin ? (1.f - ps) : h;
            outp[row] += ov * halt;
            p_sum[row] = fin ? 1.f : pn;
            if (!fin) {
                const int d = atomicAdd(&cnt[t + 1], 1);
                astore(&rnext[d], row);
            }
        }
    }
    __syncthreads();   // protect As/Bs aliases before caller reuses LDS
}

// Standalone midfin dispatch (steps 0..1).
__global__ __launch_bounds__(256) void midfin_k(
    const short* __restrict__ Snew, const short* __restrict__ P,
    const float* __restrict__ bias_p, const float* __restrict__ W_halt,
    const float* __restrict__ W2, const float* __restrict__ b2,
    float* __restrict__ outp, float* __restrict__ p_sum,
    const int* __restrict__ rprev, int* __restrict__ rnext,
    int* __restrict__ cnt, int t)
{
    __shared__ short As[TM * TK];
    __shared__ short Bs[TN * TK];
    const int n_act = cnt[t];
    for (int tile = blockIdx.x; tile * TM < n_act; tile += gridDim.x)
        midfin_tile(As, Bs, threadIdx.x, Snew, P, bias_p, W_halt, W2, b2,
                    outp, p_sum, rprev, rnext, cnt, t, tile * TM, n_act);
}

// Persistent 64-block tail: midfin(2) + steps 3..7 (gates+midfin) with
// in-kernel barriers. For this data cnt[3]==0 so the generic loop exits
// after midfin(2)+1 barrier; full loop retained for arbitrary data.
__global__ __launch_bounds__(256) void tail_k(
    const short* __restrict__ Wg, const float* __restrict__ bias_g,
    const short* __restrict__ P, const float* __restrict__ bias_p,
    const float* __restrict__ W_halt, const float* __restrict__ W2,
    const float* __restrict__ b2,
    short* __restrict__ S0, short* __restrict__ S1,
    const short* __restrict__ XB,
    float* __restrict__ cell, float* __restrict__ outp,
    float* __restrict__ p_sum,
    int* __restrict__ ridx0, int* __restrict__ ridx1,
    int* __restrict__ cnt, int* __restrict__ bar)
{
    __shared__ short As[TM * TK];
    __shared__ short Bs[TN * TK];
    const int tid = threadIdx.x;
    int phase = 0;
    int t = 2;
    while (true) {
        short* Snew = (t & 1) ? S0 : S1;        // state written by gates(t)
        const int* rprev = (t & 1) ? ridx1 : ridx0;  // L_t
        int* rnext = (t & 1) ? ridx0 : ridx1;        // L_{t+1}
        const int n = aload(&cnt[t]);
        for (int tile = blockIdx.x; tile * TM < n; tile += gridDim.x)
            midfin_tile(As, Bs, tid, Snew, P, bias_p, W_halt, W2, b2,
                        outp, p_sum, rprev, rnext, cnt, t, tile * TM, n);
        if (t == MAX_ITER - 1) break;
        ++phase; gbar(bar, phase, tid);          // publish cnt[t+1], ridx, p_sum
        const int n1 = aload(&cnt[t + 1]);
        if (n1 == 0) break;                      // uniform across blocks
        {
            short* Sot = (t & 1) ? S1 : S0;
            const int ntiles = ((n1 + TM - 1) / TM) * (NGATES / TN);
            for (int e = blockIdx.x; e < ntiles; e += gridDim.x)
                gates_tile(As, Bs, tid, Snew, XB, Wg, bias_g, cell, Sot,
                           rnext, n1, (e >> 5) * TM, e & 31);
        }
        ++phase; gbar(bar, phase, tid);          // publish Sout, cell
        ++t;
    }
}

// one dispatch for all setup: weight packing + XB + bookkeeping init.
// NOTE: S0/S1/cell are deliberately NOT initialized — at t=0 all rows are
// active, so gates(0) writes every state/cell entry before any read.
#define SETUP_XB    (BATCH * IN_DIM)
#define SETUP_WG    (NGATES * KTOT)
#define SETUP_P     (NP * HID)
#define SETUP_TOT   (SETUP_XB + SETUP_WG + SETUP_P)
__global__ __launch_bounds__(256) void setup_k(
    const float* __restrict__ x,
    const float* __restrict__ Whi, const float* __restrict__ Whf,
    const float* __restrict__ Whc, const float* __restrict__ Who,
    const float* __restrict__ Wxi, const float* __restrict__ Wxf,
    const float* __restrict__ Wxc, const float* __restrict__ Wxo,
    const float* __restrict__ bxi, const float* __restrict__ bhi,
    const float* __restrict__ bxf, const float* __restrict__ bhf,
    const float* __restrict__ bxc, const float* __restrict__ bhc,
    const float* __restrict__ bxo, const float* __restrict__ bho,
    const float* __restrict__ W1, const float* __restrict__ b1,
    const float* __restrict__ W_halt, const float* __restrict__ b_halt,
    short* __restrict__ XB,
    float* __restrict__ p_sum,
    int* __restrict__ ridx0, int* __restrict__ ridx1, int* __restrict__ cnt,
    int* __restrict__ bar, float* __restrict__ outp,
    short* __restrict__ Wg, float* __restrict__ bias_g,
    short* __restrict__ P, float* __restrict__ bias_p)
{
    int idx = blockIdx.x * 256 + threadIdx.x;
    if (idx < SETUP_XB) {
        const int row = idx >> 6, k = idx & 63;
        XB[idx] = f2bf(x[idx]);
        if (k == 0) {
            p_sum[row] = 0.f;
            outp[row] = 0.f;
            ridx0[row] = row;   // step 0: identity compaction
            ridx1[row] = 0;     // in-range dummies for padded tile reads
        }
        if (row == 0 && k <= MAX_ITER) cnt[k] = (k == 0) ? BATCH : 0;
        if (row == 1 && k == 0) bar[0] = 0;
        return;
    }
    idx -= SETUP_XB;
    if (idx < SETUP_WG) {
        const int n = idx / KTOT, k = idx - n * KTOT;
        // interleaved layout: n = 64*G + 16*g + q  ->  gate g of hidden h=16*G+q
        const int G = n >> 6, g = (n >> 4) & 3, q = n & 15;
        const int h = G * 16 + q;
        const float* Wh = (g == 0) ? Whi : (g == 1) ? Whf : (g == 2) ? Whc : Who;
        const float* Wx = (g == 0) ? Wxi : (g == 1) ? Wxf : (g == 2) ? Wxc : Wxo;
        const float v = (k < HID) ? Wh[h * HID + k] : Wx[h * IN_DIM + (k - HID)];
        Wg[idx] = f2bf(v);
        if (k == 0) {
            const float* bx = (g == 0) ? bxi : (g == 1) ? bxf : (g == 2) ? bxc : bxo;
            const float* bh = (g == 0) ? bhi : (g == 1) ? bhf : (g == 2) ? bhc : bho;
            bias_g[n] = bx[h] + bh[h];
        }
        return;
    }
    idx -= SETUP_WG;
    if (idx < SETUP_P) {
        const int n = idx >> 10, k = idx & 1023;
        const float v = (n < OMID) ? W1[n * HID + k] : (n == OMID ? W_halt[k] : 0.f);
        P[idx] = f2bf(v);
        if (k == 0) bias_p[n] = (n < OMID) ? b1[n] : (n == OMID ? b_halt[0] : 0.f);
    }
}

extern "C" void kernel_launch(void* const* d_in, const int* in_sizes, int n_in,
                              void* d_out, int out_size, void* d_ws, size_t ws_size,
                              hipStream_t stream) {
    const float* x    = (const float*)d_in[0];
    const float* Wxi  = (const float*)d_in[1];
    const float* bxi  = (const float*)d_in[2];
    const float* Whi  = (const float*)d_in[3];
    const float* bhi  = (const float*)d_in[4];
    const float* Wxf  = (const float*)d_in[5];
    const float* bxf  = (const float*)d_in[6];
    const float* Whf  = (const float*)d_in[7];
    const float* bhf  = (const float*)d_in[8];
    const float* Wxc  = (const float*)d_in[9];
    const float* bxc  = (const float*)d_in[10];
    const float* Whc  = (const float*)d_in[11];
    const float* bhc  = (const float*)d_in[12];
    const float* Wxo  = (const float*)d_in[13];
    const float* bxo  = (const float*)d_in[14];
    const float* Who  = (const float*)d_in[15];
    const float* bho  = (const float*)d_in[16];
    const float* W_halt = (const float*)d_in[17];
    const float* b_halt = (const float*)d_in[18];
    const float* W1   = (const float*)d_in[19];
    const float* b1   = (const float*)d_in[20];
    const float* W2   = (const float*)d_in[21];
    const float* b2   = (const float*)d_in[22];

    char* p = (char*)d_ws;
    auto carve = [&](size_t bytes) { char* r = p; p += (bytes + 255) & ~(size_t)255; return r; };
    short* S0     = (short*)carve((size_t)BATCH * HID * 2);
    short* S1     = (short*)carve((size_t)BATCH * HID * 2);
    short* XB     = (short*)carve((size_t)BATCH * IN_DIM * 2);
    short* Wg     = (short*)carve((size_t)NGATES * KTOT * 2);
    float* bias_g = (float*)carve((size_t)NGATES * 4);
    short* P      = (short*)carve((size_t)NP * HID * 2);
    float* bias_p = (float*)carve((size_t)NP * 4);
    float* cell   = (float*)carve((size_t)BATCH * HID * 4);
    float* p_sum  = (float*)carve((size_t)BATCH * 4);
    int*   ridx0  = (int*)carve((size_t)BATCH * 4);
    int*   ridx1  = (int*)carve((size_t)BATCH * 4);
    int*   cnt    = (int*)carve((size_t)(MAX_ITER + 1) * 4);
    int*   bar    = (int*)carve(256);
    float* outp   = (float*)d_out;

    setup_k<<<(SETUP_TOT + 255) / 256, 256, 0, stream>>>(
        x, Whi, Whf, Whc, Who, Wxi, Wxf, Wxc, Wxo,
        bxi, bhi, bxf, bhf, bxc, bhc, bxo, bho,
        W1, b1, W_halt, b_halt,
        XB, p_sum, ridx0, ridx1, cnt, bar, outp,
        Wg, bias_g, P, bias_p);

    // t=0: state==0 -> x-part only (1 k-iter from XB), cell write-only
    gates_k<<<dim3(NGATES / TN, GYD), 256, 0, stream>>>(
        S0, XB, Wg + HID, bias_g, 1, 0, 1, cell, S1, ridx0, cnt, 0);
    midfin_k<<<64, 256, 0, stream>>>(
        S1, P, bias_p, W_halt, W2, b2, outp, p_sum, ridx0, ridx1, cnt, 0);
    // t=1: full batch (64 m-tiles -> 2 dual passes/block)
    gates_k<<<dim3(NGATES / TN, GYD), 256, 0, stream>>>(
        S1, XB, Wg, bias_g, KTOT / TK, HID, 0, cell, S0, ridx1, cnt, 1);
    midfin_k<<<64, 256, 0, stream>>>(
        S0, P, bias_p, W_halt, W2, b2, outp, p_sum, ridx1, ridx0, cnt, 1);
    // t=2: ~half batch (32 m-tiles -> exactly 1 dual pass/block)
    gates_k<<<dim3(NGATES / TN, GYD), 256, 0, stream>>>(
        S0, XB, Wg, bias_g, KTOT / TK, HID, 0, cell, S1, ridx0, cnt, 2);
    // midfin(2) + steps 3..7 in one persistent 64-block kernel
    tail_k<<<TAILB, 256, 0, stream>>>(
        Wg, bias_g, P, bias_p, W_halt, W2, b2,
        S0, S1, XB, cell, outp, p_sum, ridx0, ridx1, cnt, bar);
}